// Round 3
// baseline (396.822 us; speedup 1.0000x reference)
//
#include <hip/hip_runtime.h>

// KNN (K=8) + inverse-distance-weighted average, MFMA screening version.
// data1: [N=4096, D=1024] fp32, data2: [M=8192, D=1024] fp32, out: [N, D] fp32.
//
// Fast path:
//  1) convert A -> bf16; convert B -> bf16 fused with y2[m]=||B[m]||^2
//  2) screen: bf16 MFMA GEMM, 128x128 tile per block (m97 shape), XOR-swizzled
//     LDS (2-way bank aliasing only), approx score s = y2[c] - 2*dot_bf16,
//     fused per-row top-8 per 128-col chunk (wc-halves merged in-block).
//  3) finalize: wave-per-row; 512 candidates -> approx top-16 (64-bit key
//     shfl argmin) -> EXACT fp32 rescore -> top-8 by (d2, idx) ->
//     w = 1/(sqrt(max(d2,1e-12))+0.1) -> weighted gather.
// Fallback (small ws): round-1 pure-fp32 path (verified correct).

typedef short bf16x8 __attribute__((ext_vector_type(8)));
typedef float f32x4 __attribute__((ext_vector_type(4)));

#define SENTINEL 1e30f
#define BKK 32

static __device__ __forceinline__ unsigned short f2bf(float f) {
  unsigned u = __float_as_uint(f);
  return (unsigned short)((u + 0x7fffu + ((u >> 16) & 1u)) >> 16);
}

// ---------------- fast path kernels ----------------
__global__ __launch_bounds__(256) void convert_bf16_kernel(
    const float* __restrict__ src, unsigned short* __restrict__ dst, int n4) {
  const int i = blockIdx.x * 256 + threadIdx.x;
  if (i >= n4) return;
  const float4 v = ((const float4*)src)[i];
  ushort4 o;
  o.x = f2bf(v.x); o.y = f2bf(v.y); o.z = f2bf(v.z); o.w = f2bf(v.w);
  ((ushort4*)dst)[i] = o;
}

// one block per B row: convert + row norm
__global__ __launch_bounds__(256) void convertB_norm_kernel(
    const float* __restrict__ B, unsigned short* __restrict__ Bbf,
    float* __restrict__ y2) {
  const int m = blockIdx.x;
  const int tid = threadIdx.x;
  __shared__ float red[256];
  const float4 v = ((const float4*)&B[(size_t)m * 1024])[tid];
  ushort4 o;
  o.x = f2bf(v.x); o.y = f2bf(v.y); o.z = f2bf(v.z); o.w = f2bf(v.w);
  ((ushort4*)&Bbf[(size_t)m * 1024])[tid] = o;
  red[tid] = v.x * v.x + v.y * v.y + v.z * v.z + v.w * v.w;
  __syncthreads();
  for (int s = 128; s > 0; s >>= 1) {
    if (tid < s) red[tid] += red[tid + s];
    __syncthreads();
  }
  if (tid == 0) y2[m] = red[0];
}

// grid: (M/128, N/128), 256 threads = 4 waves in 2x2; wave quadrant 64x64.
// LDS XOR swizzle: k-chunk kc of row r stored at column kc ^ ((r>>1)&3).
__global__ __launch_bounds__(256) void screen_kernel(
    const unsigned short* __restrict__ Abf, const unsigned short* __restrict__ Bbf,
    const float* __restrict__ y2g,
    float* __restrict__ cand_s, int* __restrict__ cand_i) {
  __shared__ unsigned short As[128 * 32];  // 8 KB
  __shared__ unsigned short Bs[128 * 32];  // 8 KB
  __shared__ float Scw[4][64][20];         // per-wave transpose scratch, 20 KB
  __shared__ float y2sh[128];

  const int tid = threadIdx.x;
  const int w = tid >> 6;
  const int lane = tid & 63;
  const int wr = w >> 1, wc = w & 1;
  const int r0 = blockIdx.y * 128;
  const int c0 = blockIdx.x * 128;

  if (tid < 128) y2sh[tid] = y2g[c0 + tid];

  // staging: lane -> LDS slot (row = base + lane/4, col = lane&3).
  // fetch global k-chunk kc = col ^ s(row), s(row) = (row>>1)&3 = (lane>>3)&3
  const int srow = lane >> 2;                         // 0..15
  const int sofs = ((lane & 3) ^ ((lane >> 3) & 3)) * 8;

  // fragment read: row = quadrant + lane&15, want kc = lane>>4;
  // LDS col = kc ^ s(row) = (lane>>4) ^ ((lane>>1)&3)
  const int frowA = wr * 64 + (lane & 15);
  const int frowB = wc * 64 + (lane & 15);
  const int fofs = (((lane >> 4) ^ ((lane >> 1) & 3))) * 8;

  f32x4 acc[4][4];
#pragma unroll
  for (int fi = 0; fi < 4; ++fi)
#pragma unroll
    for (int fj = 0; fj < 4; ++fj) {
      f32x4 z = {0.f, 0.f, 0.f, 0.f};
      acc[fi][fj] = z;
    }

  for (int k0 = 0; k0 < 1024; k0 += BKK) {
    const unsigned short* gA = Abf + (size_t)(r0 + w * 32 + srow) * 1024 + k0 + sofs;
    const unsigned short* gB = Bbf + (size_t)(c0 + w * 32 + srow) * 1024 + k0 + sofs;
    __syncthreads();  // previous iteration's fragment reads complete
    __builtin_amdgcn_global_load_lds(
        (const __attribute__((address_space(1))) void*)gA,
        (__attribute__((address_space(3))) void*)&As[(w * 32) * 32], 16, 0, 0);
    __builtin_amdgcn_global_load_lds(
        (const __attribute__((address_space(1))) void*)(gA + (size_t)16 * 1024),
        (__attribute__((address_space(3))) void*)&As[(w * 32 + 16) * 32], 16, 0, 0);
    __builtin_amdgcn_global_load_lds(
        (const __attribute__((address_space(1))) void*)gB,
        (__attribute__((address_space(3))) void*)&Bs[(w * 32) * 32], 16, 0, 0);
    __builtin_amdgcn_global_load_lds(
        (const __attribute__((address_space(1))) void*)(gB + (size_t)16 * 1024),
        (__attribute__((address_space(3))) void*)&Bs[(w * 32 + 16) * 32], 16, 0, 0);
    __syncthreads();  // staged data visible

    bf16x8 af[4], bfr[4];
#pragma unroll
    for (int fi = 0; fi < 4; ++fi)
      af[fi] = *(const bf16x8*)&As[(frowA + fi * 16) * 32 + fofs];
#pragma unroll
    for (int fj = 0; fj < 4; ++fj)
      bfr[fj] = *(const bf16x8*)&Bs[(frowB + fj * 16) * 32 + fofs];
#pragma unroll
    for (int fi = 0; fi < 4; ++fi)
#pragma unroll
      for (int fj = 0; fj < 4; ++fj)
        acc[fi][fj] = __builtin_amdgcn_mfma_f32_16x16x32_bf16(
            af[fi], bfr[fj], acc[fi][fj], 0, 0, 0);
  }

  // epilogue: per fj group of 16 cols, transpose via per-wave LDS, top-8
  float ts[8];
  int ti[8];
#pragma unroll
  for (int j = 0; j < 8; ++j) { ts[j] = SENTINEL; ti[j] = 0x7fffffff; }

  const int scol = lane & 15;
  const int rbase = (lane >> 4) * 4;
#pragma unroll
  for (int fj = 0; fj < 4; ++fj) {
#pragma unroll
    for (int fi = 0; fi < 4; ++fi)
#pragma unroll
      for (int rg = 0; rg < 4; ++rg)
        Scw[w][fi * 16 + rbase + rg][scol] = acc[fi][fj][rg];
    __syncthreads();
    const int cL = wc * 64 + fj * 16;  // block-local col base
    const float4 v0 = *(const float4*)&Scw[w][lane][0];
    const float4 v1 = *(const float4*)&Scw[w][lane][4];
    const float4 v2 = *(const float4*)&Scw[w][lane][8];
    const float4 v3 = *(const float4*)&Scw[w][lane][12];
    float sv[16] = {v0.x, v0.y, v0.z, v0.w, v1.x, v1.y, v1.z, v1.w,
                    v2.x, v2.y, v2.z, v2.w, v3.x, v3.y, v3.z, v3.w};
#pragma unroll
    for (int e = 0; e < 16; ++e) {
      const float s = y2sh[cL + e] - 2.0f * sv[e];
      if (s < ts[7]) {
        ts[7] = s; ti[7] = c0 + cL + e;
#pragma unroll
        for (int j = 7; j > 0; --j) {
          if (ts[j] < ts[j - 1]) {
            const float tss = ts[j]; ts[j] = ts[j - 1]; ts[j - 1] = tss;
            const int tii = ti[j]; ti[j] = ti[j - 1]; ti[j - 1] = tii;
          }
        }
      }
    }
    __syncthreads();
  }

  // merge wc=1 list into wc=0 list (same rows), one list of 8 per row/block.
  // As/Bs are dead now: overlay merge buffers (4 KB each needed, 8 KB avail).
  float* msv = (float*)As;
  int* miv = (int*)Bs;
  if (wc == 1) {
#pragma unroll
    for (int j = 0; j < 8; ++j) {
      msv[(wr * 64 + lane) * 8 + j] = ts[j];
      miv[(wr * 64 + lane) * 8 + j] = ti[j];
    }
  }
  __syncthreads();
  if (wc == 0) {
#pragma unroll
    for (int j = 0; j < 8; ++j) {
      const float s = msv[(wr * 64 + lane) * 8 + j];
      const int idx = miv[(wr * 64 + lane) * 8 + j];
      if (s < ts[7]) {  // strict <: wc=1 cols have larger indices, ties keep wc=0
        ts[7] = s; ti[7] = idx;
#pragma unroll
        for (int jj = 7; jj > 0; --jj) {
          if (ts[jj] < ts[jj - 1]) {
            const float tss = ts[jj]; ts[jj] = ts[jj - 1]; ts[jj - 1] = tss;
            const int tii = ti[jj]; ti[jj] = ti[jj - 1]; ti[jj - 1] = tii;
          }
        }
      }
    }
    const int rglob = r0 + wr * 64 + lane;
    const size_t base = ((size_t)rglob * gridDim.x + blockIdx.x) * 8;
#pragma unroll
    for (int j = 0; j < 8; ++j) {
      cand_s[base + j] = ts[j];
      cand_i[base + j] = ti[j];
    }
  }
}

// wave-per-row: grid N/4 blocks x 256 threads. 512 cand -> top-16 approx ->
// exact fp32 rescore -> top-8 -> weighted gather. Lane owns elems lane*16..+15.
__global__ __launch_bounds__(256) void finalize3_kernel(
    const float* __restrict__ A, const float* __restrict__ B,
    const float* __restrict__ y2g,
    const float* __restrict__ cand_s, const int* __restrict__ cand_i,
    float* __restrict__ out) {
  const int tid = threadIdx.x;
  const int w = tid >> 6;
  const int lane = tid & 63;
  const int n = blockIdx.x * 4 + w;
  __shared__ int mi[4][512];

  unsigned long long key[8];
#pragma unroll
  for (int i = 0; i < 8; ++i) {
    const int slot = lane + 64 * i;
    const float s = cand_s[(size_t)n * 512 + slot];
    mi[w][slot] = cand_i[(size_t)n * 512 + slot];
    unsigned u = __float_as_uint(s);
    u = (u & 0x80000000u) ? ~u : (u | 0x80000000u);
    key[i] = ((unsigned long long)u << 32) | (unsigned)slot;
  }
  __syncthreads();  // mi visible wave-wide (block barrier: simple & safe)

  int ci[16];
  for (int r = 0; r < 16; ++r) {
    unsigned long long kb = key[0];
#pragma unroll
    for (int i = 1; i < 8; ++i) kb = key[i] < kb ? key[i] : kb;
#pragma unroll
    for (int off = 32; off >= 1; off >>= 1) {
      const unsigned long long o = __shfl_xor(kb, off, 64);
      kb = o < kb ? o : kb;
    }
    const int slot = (int)(kb & 0xffffffffu);
    ci[r] = mi[w][slot];
#pragma unroll
    for (int i = 0; i < 8; ++i)
      if (slot == lane + 64 * i) key[i] = ~0ull;
  }

  // exact fp32 partial dots; lane covers 16 contiguous elements
  const float4* Arow = (const float4*)&A[(size_t)n * 1024];
  const float4 a0 = Arow[lane * 4 + 0];
  const float4 a1 = Arow[lane * 4 + 1];
  const float4 a2 = Arow[lane * 4 + 2];
  const float4 a3 = Arow[lane * 4 + 3];
  float part[17];
  part[16] = a0.x * a0.x + a0.y * a0.y + a0.z * a0.z + a0.w * a0.w +
             a1.x * a1.x + a1.y * a1.y + a1.z * a1.z + a1.w * a1.w +
             a2.x * a2.x + a2.y * a2.y + a2.z * a2.z + a2.w * a2.w +
             a3.x * a3.x + a3.y * a3.y + a3.z * a3.z + a3.w * a3.w;
#pragma unroll
  for (int j = 0; j < 16; ++j) {
    const float4* Brow = (const float4*)&B[(size_t)ci[j] * 1024];
    const float4 b0 = Brow[lane * 4 + 0];
    const float4 b1 = Brow[lane * 4 + 1];
    const float4 b2 = Brow[lane * 4 + 2];
    const float4 b3 = Brow[lane * 4 + 3];
    part[j] = a0.x * b0.x + a0.y * b0.y + a0.z * b0.z + a0.w * b0.w +
              a1.x * b1.x + a1.y * b1.y + a1.z * b1.z + a1.w * b1.w +
              a2.x * b2.x + a2.y * b2.y + a2.z * b2.z + a2.w * b2.w +
              a3.x * b3.x + a3.y * b3.y + a3.z * b3.z + a3.w * b3.w;
  }
#pragma unroll
  for (int r = 0; r < 17; ++r) {
#pragma unroll
    for (int off = 32; off >= 1; off >>= 1) part[r] += __shfl_xor(part[r], off, 64);
  }

  // all lanes hold identical totals: redundant uniform selection
  const float x2 = part[16];
  float d2v[16];
  bool used[16];
#pragma unroll
  for (int j = 0; j < 16; ++j) {
    d2v[j] = x2 + y2g[ci[j]] - 2.0f * part[j];
    used[j] = false;
  }
  float wk[8];
  int wi[8];
  float wsum = 0.0f;
  for (int k = 0; k < 8; ++k) {
    float bd = SENTINEL;
    int bi = 0x7fffffff, bslot = 0;
#pragma unroll
    for (int j = 0; j < 16; ++j) {
      if (used[j]) continue;
      const float d2 = d2v[j];
      if (d2 < bd || (d2 == bd && ci[j] < bi)) { bd = d2; bi = ci[j]; bslot = j; }
    }
    used[bslot] = true;
    const float d2c = fmaxf(bd, 1e-12f);
    const float wv = 1.0f / (sqrtf(d2c) + 0.1f);
    wk[k] = wv; wi[k] = bi; wsum += wv;
  }
  const float inv = 1.0f / wsum;

  float4 o0 = {0, 0, 0, 0}, o1 = {0, 0, 0, 0}, o2 = {0, 0, 0, 0}, o3 = {0, 0, 0, 0};
#pragma unroll
  for (int k = 0; k < 8; ++k) {
    const float wv = wk[k];
    const float4* Brow = (const float4*)&B[(size_t)wi[k] * 1024];
    const float4 b0 = Brow[lane * 4 + 0];
    const float4 b1 = Brow[lane * 4 + 1];
    const float4 b2 = Brow[lane * 4 + 2];
    const float4 b3 = Brow[lane * 4 + 3];
    o0.x += wv * b0.x; o0.y += wv * b0.y; o0.z += wv * b0.z; o0.w += wv * b0.w;
    o1.x += wv * b1.x; o1.y += wv * b1.y; o1.z += wv * b1.z; o1.w += wv * b1.w;
    o2.x += wv * b2.x; o2.y += wv * b2.y; o2.z += wv * b2.z; o2.w += wv * b2.w;
    o3.x += wv * b3.x; o3.y += wv * b3.y; o3.z += wv * b3.z; o3.w += wv * b3.w;
  }
  float4* Orow = (float4*)&out[(size_t)n * 1024];
  o0.x *= inv; o0.y *= inv; o0.z *= inv; o0.w *= inv;
  o1.x *= inv; o1.y *= inv; o1.z *= inv; o1.w *= inv;
  o2.x *= inv; o2.y *= inv; o2.z *= inv; o2.w *= inv;
  o3.x *= inv; o3.y *= inv; o3.z *= inv; o3.w *= inv;
  Orow[lane * 4 + 0] = o0;
  Orow[lane * 4 + 1] = o1;
  Orow[lane * 4 + 2] = o2;
  Orow[lane * 4 + 3] = o3;
}

// ---------------- fallback path (round-1, verified) ----------------
__global__ __launch_bounds__(256) void rownorm_kernel(
    const float* __restrict__ B, float* __restrict__ y2) {
  const int m = blockIdx.x;
  const int tid = threadIdx.x;
  __shared__ float red[256];
  const float4 v = *(const float4*)&B[(size_t)m * 1024 + tid * 4];
  red[tid] = v.x * v.x + v.y * v.y + v.z * v.z + v.w * v.w;
  __syncthreads();
  for (int s = 128; s > 0; s >>= 1) {
    if (tid < s) red[tid] += red[tid + s];
    __syncthreads();
  }
  if (tid == 0) y2[m] = red[0];
}

__global__ __launch_bounds__(256) void knn_chunk_kernel(
    const float* __restrict__ A, const float* __restrict__ B,
    const float* __restrict__ y2g,
    float* __restrict__ cand_s, int* __restrict__ cand_i) {
  __shared__ float As[BKK][68];
  __shared__ float Bs[BKK][68];
  __shared__ float Sc[64][65];

  const int tid = threadIdx.x;
  const int tx = tid & 15;
  const int ty = tid >> 4;
  const int r0 = blockIdx.y * 64;
  const int c0 = blockIdx.x * 1024;
  const int lrow = tid >> 3;
  const int lk = (tid & 7) * 4;

  float top_s[8];
  int top_i[8];
#pragma unroll
  for (int j = 0; j < 8; ++j) { top_s[j] = SENTINEL; top_i[j] = 0x7fffffff; }

  for (int tile = 0; tile < 16; ++tile) {
    const int cbase = c0 + tile * 64;
    float acc[4][4];
#pragma unroll
    for (int i = 0; i < 4; ++i)
#pragma unroll
      for (int j = 0; j < 4; ++j) acc[i][j] = 0.0f;

    for (int k0 = 0; k0 < 1024; k0 += BKK) {
      const float4 a0 = *(const float4*)&A[(size_t)(r0 + lrow) * 1024 + k0 + lk];
      const float4 a1 = *(const float4*)&A[(size_t)(r0 + lrow + 32) * 1024 + k0 + lk];
      const float4 b0 = *(const float4*)&B[(size_t)(cbase + lrow) * 1024 + k0 + lk];
      const float4 b1 = *(const float4*)&B[(size_t)(cbase + lrow + 32) * 1024 + k0 + lk];
      __syncthreads();
      As[lk + 0][lrow] = a0.x; As[lk + 1][lrow] = a0.y;
      As[lk + 2][lrow] = a0.z; As[lk + 3][lrow] = a0.w;
      As[lk + 0][lrow + 32] = a1.x; As[lk + 1][lrow + 32] = a1.y;
      As[lk + 2][lrow + 32] = a1.z; As[lk + 3][lrow + 32] = a1.w;
      Bs[lk + 0][lrow] = b0.x; Bs[lk + 1][lrow] = b0.y;
      Bs[lk + 2][lrow] = b0.z; Bs[lk + 3][lrow] = b0.w;
      Bs[lk + 0][lrow + 32] = b1.x; Bs[lk + 1][lrow + 32] = b1.y;
      Bs[lk + 2][lrow + 32] = b1.z; Bs[lk + 3][lrow + 32] = b1.w;
      __syncthreads();
#pragma unroll
      for (int kk = 0; kk < BKK; ++kk) {
        const float4 av = *(const float4*)&As[kk][ty * 4];
        const float4 bv = *(const float4*)&Bs[kk][tx * 4];
        acc[0][0] += av.x * bv.x; acc[0][1] += av.x * bv.y;
        acc[0][2] += av.x * bv.z; acc[0][3] += av.x * bv.w;
        acc[1][0] += av.y * bv.x; acc[1][1] += av.y * bv.y;
        acc[1][2] += av.y * bv.z; acc[1][3] += av.y * bv.w;
        acc[2][0] += av.z * bv.x; acc[2][1] += av.z * bv.y;
        acc[2][2] += av.z * bv.z; acc[2][3] += av.z * bv.w;
        acc[3][0] += av.w * bv.x; acc[3][1] += av.w * bv.y;
        acc[3][2] += av.w * bv.z; acc[3][3] += av.w * bv.w;
      }
    }
#pragma unroll
    for (int i = 0; i < 4; ++i) {
      const int row = ty * 4 + i;
#pragma unroll
      for (int j = 0; j < 4; ++j) {
        const int col = tx * 4 + j;
        Sc[row][col] = y2g[cbase + col] - 2.0f * acc[i][j];
      }
    }
    __syncthreads();
    if (tid < 64) {
      for (int c = 0; c < 64; ++c) {
        const float s = Sc[tid][c];
        if (s < top_s[7]) {
          top_s[7] = s; top_i[7] = cbase + c;
#pragma unroll
          for (int j = 7; j > 0; --j) {
            if (top_s[j] < top_s[j - 1]) {
              const float tss = top_s[j]; top_s[j] = top_s[j - 1]; top_s[j - 1] = tss;
              const int tii = top_i[j]; top_i[j] = top_i[j - 1]; top_i[j - 1] = tii;
            }
          }
        }
      }
    }
  }

  if (tid < 64) {
    const int n = r0 + tid;
    const int base = (n * gridDim.x + blockIdx.x) * 8;
#pragma unroll
    for (int j = 0; j < 8; ++j) {
      cand_s[base + j] = top_s[j];
      cand_i[base + j] = top_i[j];
    }
  }
}

__global__ __launch_bounds__(256) void finalize_kernel(
    const float* __restrict__ A, const float* __restrict__ B,
    const float* __restrict__ cand_s, const int* __restrict__ cand_i,
    float* __restrict__ out, int nchunks) {
  const int n = blockIdx.x;
  const int tid = threadIdx.x;
  __shared__ float red[256];
  __shared__ float ls[64];
  __shared__ int li[64];
  __shared__ float wsh2[8];
  __shared__ int wid[8];
  __shared__ float wsum_sh;

  const int ncand = nchunks * 8;
  const float4 a = *(const float4*)&A[(size_t)n * 1024 + tid * 4];
  red[tid] = a.x * a.x + a.y * a.y + a.z * a.z + a.w * a.w;
  if (tid < ncand) {
    ls[tid] = cand_s[n * ncand + tid];
    li[tid] = cand_i[n * ncand + tid];
  }
  __syncthreads();
  for (int s = 128; s > 0; s >>= 1) {
    if (tid < s) red[tid] += red[tid + s];
    __syncthreads();
  }
  if (tid == 0) {
    const float x2 = red[0];
    float wsum = 0.0f;
    for (int j = 0; j < 8; ++j) {
      float bs = SENTINEL;
      int bi = 0x7fffffff;
      int bp = 0;
      for (int c = 0; c < ncand; ++c) {
        const float s_ = ls[c];
        const int i_ = li[c];
        if (s_ < bs || (s_ == bs && i_ < bi)) { bs = s_; bi = i_; bp = c; }
      }
      ls[bp] = SENTINEL; li[bp] = 0x7fffffff;
      float d2 = x2 + bs;
      d2 = fmaxf(d2, 1e-12f);
      const float wkk = 1.0f / (sqrtf(d2) + 0.1f);
      wsh2[j] = wkk; wid[j] = bi;
      wsum += wkk;
    }
    wsum_sh = wsum;
  }
  __syncthreads();
  const float inv = 1.0f / wsum_sh;
  float ox = 0.0f, oy = 0.0f, oz = 0.0f, ow = 0.0f;
#pragma unroll
  for (int j = 0; j < 8; ++j) {
    const float wkk = wsh2[j];
    const float4 v = *(const float4*)&B[(size_t)wid[j] * 1024 + tid * 4];
    ox += wkk * v.x; oy += wkk * v.y; oz += wkk * v.z; ow += wkk * v.w;
  }
  float4 o;
  o.x = ox * inv; o.y = oy * inv; o.z = oz * inv; o.w = ow * inv;
  *(float4*)&out[(size_t)n * 1024 + tid * 4] = o;
}

extern "C" void kernel_launch(void* const* d_in, const int* in_sizes, int n_in,
                              void* d_out, int out_size, void* d_ws, size_t ws_size,
                              hipStream_t stream) {
  const float* A = (const float*)d_in[0];
  const float* Bm = (const float*)d_in[1];
  const int D = 1024;
  const int N = in_sizes[0] / D;  // 4096
  const int M = in_sizes[1] / D;  // 8192

  const size_t needA = (size_t)N * D * 2;
  const size_t needB = (size_t)M * D * 2;
  const size_t needC = (size_t)N * 512 * 4;  // cand_s (== cand_i)
  const size_t need = needA + needB + (size_t)M * 4 + 2 * needC;

  if (ws_size >= need && M == 8192 && N % 128 == 0) {
    unsigned short* Abf = (unsigned short*)d_ws;
    unsigned short* Bbf = Abf + (size_t)N * D;
    float* y2 = (float*)(Bbf + (size_t)M * D);
    float* cand_s = y2 + M;
    int* cand_i = (int*)(cand_s + (size_t)N * 512);

    convert_bf16_kernel<<<(N * D / 4 + 255) / 256, 256, 0, stream>>>(A, Abf, N * D / 4);
    convertB_norm_kernel<<<M, 256, 0, stream>>>(Bm, Bbf, y2);
    dim3 g(M / 128, N / 128);
    screen_kernel<<<g, 256, 0, stream>>>(Abf, Bbf, y2, cand_s, cand_i);
    finalize3_kernel<<<N / 4, 256, 0, stream>>>(A, Bm, y2, cand_s, cand_i,
                                                (float*)d_out);
  } else {
    float* y2 = (float*)d_ws;
    float* cand_s = y2 + M;
    int* cand_i = (int*)(cand_s + (size_t)N * 64);
    rownorm_kernel<<<M, 256, 0, stream>>>(Bm, y2);
    dim3 gridB(M / 1024, N / 64);
    knn_chunk_kernel<<<gridB, 256, 0, stream>>>(A, Bm, y2, cand_s, cand_i);
    finalize_kernel<<<N, 256, 0, stream>>>(A, Bm, cand_s, cand_i, (float*)d_out, M / 1024);
  }
}

// Round 4
// 380.847 us; speedup vs baseline: 1.0419x; 1.0419x over previous
//
#include <hip/hip_runtime.h>

// KNN (K=8) + inverse-distance-weighted average, MFMA screening version.
// data1: [N=4096, D=1024] fp32, data2: [M=8192, D=1024] fp32, out: [N, D] fp32.
//
// Fast path:
//  1) convert_all: A -> bf16; B -> bf16 fused with y2[m]=||B[m]||^2
//  2) screen2: bf16 MFMA GEMM, 128x256 tile per block, acc[4][8] (128 VGPR),
//     32 MFMA per barrier pair, XOR-swizzled LDS, approx s = y2[c]-2*dot_bf16,
//     per-row top-8 per 256-col block (wc halves merged in-block) -> 256 cands.
//  3) finalize3: wave-per-row; 256 cands -> approx top-16 (64-bit key shfl
//     argmin) -> EXACT fp32 rescore -> top-8 by (d2, idx) ->
//     w = 1/(sqrt(max(d2,1e-12))+0.1) -> weighted gather.
// Fallback (small ws): round-1 pure-fp32 path (verified correct).

typedef short bf16x8 __attribute__((ext_vector_type(8)));
typedef float f32x4 __attribute__((ext_vector_type(4)));

#define SENTINEL 1e30f
#define BKK 32

static __device__ __forceinline__ unsigned short f2bf(float f) {
  unsigned u = __float_as_uint(f);
  return (unsigned short)((u + 0x7fffu + ((u >> 16) & 1u)) >> 16);
}

// ---------------- fast path kernels ----------------
// grid: N + M blocks. bid < N: convert A row. else: convert B row + norm.
__global__ __launch_bounds__(256) void convert_all_kernel(
    const float* __restrict__ A, const float* __restrict__ B,
    unsigned short* __restrict__ Abf, unsigned short* __restrict__ Bbf,
    float* __restrict__ y2, int N) {
  const int bid = blockIdx.x;
  const int tid = threadIdx.x;
  if (bid < N) {
    const float4 v = ((const float4*)&A[(size_t)bid * 1024])[tid];
    ushort4 o;
    o.x = f2bf(v.x); o.y = f2bf(v.y); o.z = f2bf(v.z); o.w = f2bf(v.w);
    ((ushort4*)&Abf[(size_t)bid * 1024])[tid] = o;
  } else {
    const int m = bid - N;
    __shared__ float red[256];
    const float4 v = ((const float4*)&B[(size_t)m * 1024])[tid];
    ushort4 o;
    o.x = f2bf(v.x); o.y = f2bf(v.y); o.z = f2bf(v.z); o.w = f2bf(v.w);
    ((ushort4*)&Bbf[(size_t)m * 1024])[tid] = o;
    red[tid] = v.x * v.x + v.y * v.y + v.z * v.z + v.w * v.w;
    __syncthreads();
    for (int s = 128; s > 0; s >>= 1) {
      if (tid < s) red[tid] += red[tid + s];
      __syncthreads();
    }
    if (tid == 0) y2[m] = red[0];
  }
}

// grid: (M/256, N/128), 256 threads = 4 waves (2 row-halves x 2 col-halves).
// Per wave: 64 rows x 128 cols, 4x8 fragments of 16x16x32 bf16 MFMA.
// LDS XOR swizzle: k-chunk kc of row r stored at column kc ^ ((r>>1)&3).
__global__ __launch_bounds__(256, 2) void screen2_kernel(
    const unsigned short* __restrict__ Abf, const unsigned short* __restrict__ Bbf,
    const float* __restrict__ y2g,
    float* __restrict__ cand_s, int* __restrict__ cand_i) {
  __shared__ alignas(16) char pool[24 * 1024];  // As 8K | Bs 16K; epilogue reuse
  __shared__ float y2sh[256];
  unsigned short* As = (unsigned short*)pool;           // [128][32]
  unsigned short* Bs = (unsigned short*)(pool + 8192);  // [256][32]

  const int tid = threadIdx.x;
  const int w = tid >> 6;
  const int lane = tid & 63;
  const int wr = w >> 1, wc = w & 1;
  const int r0 = blockIdx.y * 128;
  const int c0 = blockIdx.x * 256;

  y2sh[tid] = y2g[c0 + tid];

  // staging: lane -> LDS slot (16 rows per glds), swizzle on global source
  const int srow = lane >> 2;                          // 0..15
  const int sofs = ((lane & 3) ^ ((lane >> 3) & 3)) * 8;

  // fragment reads: LDS col = kc ^ ((row>>1)&3), kc = lane>>4
  const int frowA = wr * 64 + (lane & 15);
  const int frowB = wc * 128 + (lane & 15);
  const int fofs = ((lane >> 4) ^ ((lane >> 1) & 3)) * 8;

  f32x4 acc[4][8];
#pragma unroll
  for (int fi = 0; fi < 4; ++fi)
#pragma unroll
    for (int fj = 0; fj < 8; ++fj) {
      f32x4 z = {0.f, 0.f, 0.f, 0.f};
      acc[fi][fj] = z;
    }

  for (int k0 = 0; k0 < 1024; k0 += BKK) {
    const unsigned short* gA =
        Abf + (size_t)(r0 + w * 32 + srow) * 1024 + k0 + sofs;
    const unsigned short* gB =
        Bbf + (size_t)(c0 + w * 64 + srow) * 1024 + k0 + sofs;
    __syncthreads();  // previous iteration's fragment reads complete
    __builtin_amdgcn_global_load_lds(
        (const __attribute__((address_space(1))) void*)gA,
        (__attribute__((address_space(3))) void*)&As[(w * 32) * 32], 16, 0, 0);
    __builtin_amdgcn_global_load_lds(
        (const __attribute__((address_space(1))) void*)(gA + (size_t)16 * 1024),
        (__attribute__((address_space(3))) void*)&As[(w * 32 + 16) * 32], 16, 0, 0);
#pragma unroll
    for (int l = 0; l < 4; ++l)
      __builtin_amdgcn_global_load_lds(
          (const __attribute__((address_space(1))) void*)(gB + (size_t)(16 * l) * 1024),
          (__attribute__((address_space(3))) void*)&Bs[(w * 64 + 16 * l) * 32], 16, 0, 0);
    __syncthreads();  // staged data visible

    bf16x8 af[4], bfr[8];
#pragma unroll
    for (int fi = 0; fi < 4; ++fi)
      af[fi] = *(const bf16x8*)&As[(frowA + fi * 16) * 32 + fofs];
#pragma unroll
    for (int fj = 0; fj < 8; ++fj)
      bfr[fj] = *(const bf16x8*)&Bs[(frowB + fj * 16) * 32 + fofs];
#pragma unroll
    for (int fi = 0; fi < 4; ++fi)
#pragma unroll
      for (int fj = 0; fj < 8; ++fj)
        acc[fi][fj] = __builtin_amdgcn_mfma_f32_16x16x32_bf16(
            af[fi], bfr[fj], acc[fi][fj], 0, 0, 0);
  }
  __syncthreads();  // all fragment reads done: As/Bs pool is dead, reuse it

  // epilogue: per fj group of 16 cols, transpose via per-wave scratch, top-8
  float (*Scw)[64][20] = (float(*)[64][20])pool;  // [4][64][20] = 20 KB

  float ts[8];
  int ti[8];
#pragma unroll
  for (int j = 0; j < 8; ++j) { ts[j] = SENTINEL; ti[j] = 0x7fffffff; }

  const int scol = lane & 15;
  const int rbase = (lane >> 4) * 4;
#pragma unroll
  for (int fj = 0; fj < 8; ++fj) {
#pragma unroll
    for (int fi = 0; fi < 4; ++fi)
#pragma unroll
      for (int rg = 0; rg < 4; ++rg)
        Scw[w][fi * 16 + rbase + rg][scol] = acc[fi][fj][rg];
    __syncthreads();
    const int cL = wc * 128 + fj * 16;  // block-local col base
    const float4 v0 = *(const float4*)&Scw[w][lane][0];
    const float4 v1 = *(const float4*)&Scw[w][lane][4];
    const float4 v2 = *(const float4*)&Scw[w][lane][8];
    const float4 v3 = *(const float4*)&Scw[w][lane][12];
    float sv[16] = {v0.x, v0.y, v0.z, v0.w, v1.x, v1.y, v1.z, v1.w,
                    v2.x, v2.y, v2.z, v2.w, v3.x, v3.y, v3.z, v3.w};
#pragma unroll
    for (int e = 0; e < 16; ++e) {
      const float s = y2sh[cL + e] - 2.0f * sv[e];
      if (s < ts[7]) {
        ts[7] = s; ti[7] = c0 + cL + e;
#pragma unroll
        for (int j = 7; j > 0; --j) {
          if (ts[j] < ts[j - 1]) {
            const float tss = ts[j]; ts[j] = ts[j - 1]; ts[j - 1] = tss;
            const int tii = ti[j]; ti[j] = ti[j - 1]; ti[j - 1] = tii;
          }
        }
      }
    }
    __syncthreads();
  }

  // merge wc=1 list into wc=0 list (same rows) -> 8 cands per row per block
  float* msv = (float*)pool;           // 128*8 floats = 4 KB
  int* miv = (int*)(pool + 4096);      // 4 KB
  if (wc == 1) {
#pragma unroll
    for (int j = 0; j < 8; ++j) {
      msv[(wr * 64 + lane) * 8 + j] = ts[j];
      miv[(wr * 64 + lane) * 8 + j] = ti[j];
    }
  }
  __syncthreads();
  if (wc == 0) {
#pragma unroll
    for (int j = 0; j < 8; ++j) {
      const float s = msv[(wr * 64 + lane) * 8 + j];
      const int idx = miv[(wr * 64 + lane) * 8 + j];
      if (s < ts[7]) {  // ties (measure-zero) washed by top-16 rescore window
        ts[7] = s; ti[7] = idx;
#pragma unroll
        for (int jj = 7; jj > 0; --jj) {
          if (ts[jj] < ts[jj - 1]) {
            const float tss = ts[jj]; ts[jj] = ts[jj - 1]; ts[jj - 1] = tss;
            const int tii = ti[jj]; ti[jj] = ti[jj - 1]; ti[jj - 1] = tii;
          }
        }
      }
    }
    const int rglob = r0 + wr * 64 + lane;
    const size_t base = ((size_t)rglob * gridDim.x + blockIdx.x) * 8;
#pragma unroll
    for (int j = 0; j < 8; ++j) {
      cand_s[base + j] = ts[j];
      cand_i[base + j] = ti[j];
    }
  }
}

// wave-per-row: grid N/4 blocks x 256 threads. 256 cand -> top-16 approx ->
// exact fp32 rescore -> top-8 -> weighted gather. Lane owns elems lane*16..+15.
__global__ __launch_bounds__(256) void finalize3_kernel(
    const float* __restrict__ A, const float* __restrict__ B,
    const float* __restrict__ y2g,
    const float* __restrict__ cand_s, const int* __restrict__ cand_i,
    float* __restrict__ out) {
  const int tid = threadIdx.x;
  const int w = tid >> 6;
  const int lane = tid & 63;
  const int n = blockIdx.x * 4 + w;
  __shared__ int mi[4][256];

  unsigned long long key[4];
#pragma unroll
  for (int i = 0; i < 4; ++i) {
    const int slot = lane + 64 * i;
    const float s = cand_s[(size_t)n * 256 + slot];
    mi[w][slot] = cand_i[(size_t)n * 256 + slot];
    unsigned u = __float_as_uint(s);
    u = (u & 0x80000000u) ? ~u : (u | 0x80000000u);
    key[i] = ((unsigned long long)u << 32) | (unsigned)slot;
  }
  __syncthreads();

  int ci[16];
  for (int r = 0; r < 16; ++r) {
    unsigned long long kb = key[0];
#pragma unroll
    for (int i = 1; i < 4; ++i) kb = key[i] < kb ? key[i] : kb;
#pragma unroll
    for (int off = 32; off >= 1; off >>= 1) {
      const unsigned long long o = __shfl_xor(kb, off, 64);
      kb = o < kb ? o : kb;
    }
    const int slot = (int)(kb & 0xffffffffu);
    ci[r] = mi[w][slot];
#pragma unroll
    for (int i = 0; i < 4; ++i)
      if (slot == lane + 64 * i) key[i] = ~0ull;
  }

  // exact fp32 partial dots; lane covers 16 contiguous elements
  const float4* Arow = (const float4*)&A[(size_t)n * 1024];
  const float4 a0 = Arow[lane * 4 + 0];
  const float4 a1 = Arow[lane * 4 + 1];
  const float4 a2 = Arow[lane * 4 + 2];
  const float4 a3 = Arow[lane * 4 + 3];
  float part[17];
  part[16] = a0.x * a0.x + a0.y * a0.y + a0.z * a0.z + a0.w * a0.w +
             a1.x * a1.x + a1.y * a1.y + a1.z * a1.z + a1.w * a1.w +
             a2.x * a2.x + a2.y * a2.y + a2.z * a2.z + a2.w * a2.w +
             a3.x * a3.x + a3.y * a3.y + a3.z * a3.z + a3.w * a3.w;
#pragma unroll
  for (int j = 0; j < 16; ++j) {
    const float4* Brow = (const float4*)&B[(size_t)ci[j] * 1024];
    const float4 b0 = Brow[lane * 4 + 0];
    const float4 b1 = Brow[lane * 4 + 1];
    const float4 b2 = Brow[lane * 4 + 2];
    const float4 b3 = Brow[lane * 4 + 3];
    part[j] = a0.x * b0.x + a0.y * b0.y + a0.z * b0.z + a0.w * b0.w +
              a1.x * b1.x + a1.y * b1.y + a1.z * b1.z + a1.w * b1.w +
              a2.x * b2.x + a2.y * b2.y + a2.z * b2.z + a2.w * b2.w +
              a3.x * b3.x + a3.y * b3.y + a3.z * b3.z + a3.w * b3.w;
  }
#pragma unroll
  for (int r = 0; r < 17; ++r) {
#pragma unroll
    for (int off = 32; off >= 1; off >>= 1) part[r] += __shfl_xor(part[r], off, 64);
  }

  // all lanes hold identical totals: redundant uniform selection
  const float x2 = part[16];
  float d2v[16];
  bool used[16];
#pragma unroll
  for (int j = 0; j < 16; ++j) {
    d2v[j] = x2 + y2g[ci[j]] - 2.0f * part[j];
    used[j] = false;
  }
  float wk[8];
  int wi[8];
  float wsum = 0.0f;
  for (int k = 0; k < 8; ++k) {
    float bd = SENTINEL;
    int bi = 0x7fffffff, bslot = 0;
#pragma unroll
    for (int j = 0; j < 16; ++j) {
      if (used[j]) continue;
      const float d2 = d2v[j];
      if (d2 < bd || (d2 == bd && ci[j] < bi)) { bd = d2; bi = ci[j]; bslot = j; }
    }
    used[bslot] = true;
    const float d2c = fmaxf(bd, 1e-12f);
    const float wv = 1.0f / (sqrtf(d2c) + 0.1f);
    wk[k] = wv; wi[k] = bi; wsum += wv;
  }
  const float inv = 1.0f / wsum;

  float4 o0 = {0, 0, 0, 0}, o1 = {0, 0, 0, 0}, o2 = {0, 0, 0, 0}, o3 = {0, 0, 0, 0};
#pragma unroll
  for (int k = 0; k < 8; ++k) {
    const float wv = wk[k];
    const float4* Brow = (const float4*)&B[(size_t)wi[k] * 1024];
    const float4 b0 = Brow[lane * 4 + 0];
    const float4 b1 = Brow[lane * 4 + 1];
    const float4 b2 = Brow[lane * 4 + 2];
    const float4 b3 = Brow[lane * 4 + 3];
    o0.x += wv * b0.x; o0.y += wv * b0.y; o0.z += wv * b0.z; o0.w += wv * b0.w;
    o1.x += wv * b1.x; o1.y += wv * b1.y; o1.z += wv * b1.z; o1.w += wv * b1.w;
    o2.x += wv * b2.x; o2.y += wv * b2.y; o2.z += wv * b2.z; o2.w += wv * b2.w;
    o3.x += wv * b3.x; o3.y += wv * b3.y; o3.z += wv * b3.z; o3.w += wv * b3.w;
  }
  float4* Orow = (float4*)&out[(size_t)n * 1024];
  o0.x *= inv; o0.y *= inv; o0.z *= inv; o0.w *= inv;
  o1.x *= inv; o1.y *= inv; o1.z *= inv; o1.w *= inv;
  o2.x *= inv; o2.y *= inv; o2.z *= inv; o2.w *= inv;
  o3.x *= inv; o3.y *= inv; o3.z *= inv; o3.w *= inv;
  Orow[lane * 4 + 0] = o0;
  Orow[lane * 4 + 1] = o1;
  Orow[lane * 4 + 2] = o2;
  Orow[lane * 4 + 3] = o3;
}

// ---------------- fallback path (round-1, verified) ----------------
__global__ __launch_bounds__(256) void rownorm_kernel(
    const float* __restrict__ B, float* __restrict__ y2) {
  const int m = blockIdx.x;
  const int tid = threadIdx.x;
  __shared__ float red[256];
  const float4 v = *(const float4*)&B[(size_t)m * 1024 + tid * 4];
  red[tid] = v.x * v.x + v.y * v.y + v.z * v.z + v.w * v.w;
  __syncthreads();
  for (int s = 128; s > 0; s >>= 1) {
    if (tid < s) red[tid] += red[tid + s];
    __syncthreads();
  }
  if (tid == 0) y2[m] = red[0];
}

__global__ __launch_bounds__(256) void knn_chunk_kernel(
    const float* __restrict__ A, const float* __restrict__ B,
    const float* __restrict__ y2g,
    float* __restrict__ cand_s, int* __restrict__ cand_i) {
  __shared__ float As[BKK][68];
  __shared__ float Bs[BKK][68];
  __shared__ float Sc[64][65];

  const int tid = threadIdx.x;
  const int tx = tid & 15;
  const int ty = tid >> 4;
  const int r0 = blockIdx.y * 64;
  const int c0 = blockIdx.x * 1024;
  const int lrow = tid >> 3;
  const int lk = (tid & 7) * 4;

  float top_s[8];
  int top_i[8];
#pragma unroll
  for (int j = 0; j < 8; ++j) { top_s[j] = SENTINEL; top_i[j] = 0x7fffffff; }

  for (int tile = 0; tile < 16; ++tile) {
    const int cbase = c0 + tile * 64;
    float acc[4][4];
#pragma unroll
    for (int i = 0; i < 4; ++i)
#pragma unroll
      for (int j = 0; j < 4; ++j) acc[i][j] = 0.0f;

    for (int k0 = 0; k0 < 1024; k0 += BKK) {
      const float4 a0 = *(const float4*)&A[(size_t)(r0 + lrow) * 1024 + k0 + lk];
      const float4 a1 = *(const float4*)&A[(size_t)(r0 + lrow + 32) * 1024 + k0 + lk];
      const float4 b0 = *(const float4*)&B[(size_t)(cbase + lrow) * 1024 + k0 + lk];
      const float4 b1 = *(const float4*)&B[(size_t)(cbase + lrow + 32) * 1024 + k0 + lk];
      __syncthreads();
      As[lk + 0][lrow] = a0.x; As[lk + 1][lrow] = a0.y;
      As[lk + 2][lrow] = a0.z; As[lk + 3][lrow] = a0.w;
      As[lk + 0][lrow + 32] = a1.x; As[lk + 1][lrow + 32] = a1.y;
      As[lk + 2][lrow + 32] = a1.z; As[lk + 3][lrow + 32] = a1.w;
      Bs[lk + 0][lrow] = b0.x; Bs[lk + 1][lrow] = b0.y;
      Bs[lk + 2][lrow] = b0.z; Bs[lk + 3][lrow] = b0.w;
      Bs[lk + 0][lrow + 32] = b1.x; Bs[lk + 1][lrow + 32] = b1.y;
      Bs[lk + 2][lrow + 32] = b1.z; Bs[lk + 3][lrow + 32] = b1.w;
      __syncthreads();
#pragma unroll
      for (int kk = 0; kk < BKK; ++kk) {
        const float4 av = *(const float4*)&As[kk][ty * 4];
        const float4 bv = *(const float4*)&Bs[kk][tx * 4];
        acc[0][0] += av.x * bv.x; acc[0][1] += av.x * bv.y;
        acc[0][2] += av.x * bv.z; acc[0][3] += av.x * bv.w;
        acc[1][0] += av.y * bv.x; acc[1][1] += av.y * bv.y;
        acc[1][2] += av.y * bv.z; acc[1][3] += av.y * bv.w;
        acc[2][0] += av.z * bv.x; acc[2][1] += av.z * bv.y;
        acc[2][2] += av.z * bv.z; acc[2][3] += av.z * bv.w;
        acc[3][0] += av.w * bv.x; acc[3][1] += av.w * bv.y;
        acc[3][2] += av.w * bv.z; acc[3][3] += av.w * bv.w;
      }
    }
#pragma unroll
    for (int i = 0; i < 4; ++i) {
      const int row = ty * 4 + i;
#pragma unroll
      for (int j = 0; j < 4; ++j) {
        const int col = tx * 4 + j;
        Sc[row][col] = y2g[cbase + col] - 2.0f * acc[i][j];
      }
    }
    __syncthreads();
    if (tid < 64) {
      for (int c = 0; c < 64; ++c) {
        const float s = Sc[tid][c];
        if (s < top_s[7]) {
          top_s[7] = s; top_i[7] = cbase + c;
#pragma unroll
          for (int j = 7; j > 0; --j) {
            if (top_s[j] < top_s[j - 1]) {
              const float tss = top_s[j]; top_s[j] = top_s[j - 1]; top_s[j - 1] = tss;
              const int tii = top_i[j]; top_i[j] = top_i[j - 1]; top_i[j - 1] = tii;
            }
          }
        }
      }
    }
  }

  if (tid < 64) {
    const int n = r0 + tid;
    const int base = (n * gridDim.x + blockIdx.x) * 8;
#pragma unroll
    for (int j = 0; j < 8; ++j) {
      cand_s[base + j] = top_s[j];
      cand_i[base + j] = top_i[j];
    }
  }
}

__global__ __launch_bounds__(256) void finalize_kernel(
    const float* __restrict__ A, const float* __restrict__ B,
    const float* __restrict__ cand_s, const int* __restrict__ cand_i,
    float* __restrict__ out, int nchunks) {
  const int n = blockIdx.x;
  const int tid = threadIdx.x;
  __shared__ float red[256];
  __shared__ float ls[64];
  __shared__ int li[64];
  __shared__ float wsh2[8];
  __shared__ int wid[8];
  __shared__ float wsum_sh;

  const int ncand = nchunks * 8;
  const float4 a = *(const float4*)&A[(size_t)n * 1024 + tid * 4];
  red[tid] = a.x * a.x + a.y * a.y + a.z * a.z + a.w * a.w;
  if (tid < ncand) {
    ls[tid] = cand_s[n * ncand + tid];
    li[tid] = cand_i[n * ncand + tid];
  }
  __syncthreads();
  for (int s = 128; s > 0; s >>= 1) {
    if (tid < s) red[tid] += red[tid + s];
    __syncthreads();
  }
  if (tid == 0) {
    const float x2 = red[0];
    float wsum = 0.0f;
    for (int j = 0; j < 8; ++j) {
      float bs = SENTINEL;
      int bi = 0x7fffffff;
      int bp = 0;
      for (int c = 0; c < ncand; ++c) {
        const float s_ = ls[c];
        const int i_ = li[c];
        if (s_ < bs || (s_ == bs && i_ < bi)) { bs = s_; bi = i_; bp = c; }
      }
      ls[bp] = SENTINEL; li[bp] = 0x7fffffff;
      float d2 = x2 + bs;
      d2 = fmaxf(d2, 1e-12f);
      const float wkk = 1.0f / (sqrtf(d2) + 0.1f);
      wsh2[j] = wkk; wid[j] = bi;
      wsum += wkk;
    }
    wsum_sh = wsum;
  }
  __syncthreads();
  const float inv = 1.0f / wsum_sh;
  float ox = 0.0f, oy = 0.0f, oz = 0.0f, ow = 0.0f;
#pragma unroll
  for (int j = 0; j < 8; ++j) {
    const float wkk = wsh2[j];
    const float4 v = *(const float4*)&B[(size_t)wid[j] * 1024 + tid * 4];
    ox += wkk * v.x; oy += wkk * v.y; oz += wkk * v.z; ow += wkk * v.w;
  }
  float4 o;
  o.x = ox * inv; o.y = oy * inv; o.z = oz * inv; o.w = ow * inv;
  *(float4*)&out[(size_t)n * 1024 + tid * 4] = o;
}

extern "C" void kernel_launch(void* const* d_in, const int* in_sizes, int n_in,
                              void* d_out, int out_size, void* d_ws, size_t ws_size,
                              hipStream_t stream) {
  const float* A = (const float*)d_in[0];
  const float* Bm = (const float*)d_in[1];
  const int D = 1024;
  const int N = in_sizes[0] / D;  // 4096
  const int M = in_sizes[1] / D;  // 8192

  const size_t needA = (size_t)N * D * 2;
  const size_t needB = (size_t)M * D * 2;
  const size_t needC = (size_t)N * 256 * 4;  // cand_s (== cand_i)
  const size_t need = needA + needB + (size_t)M * 4 + 2 * needC;

  if (ws_size >= need && M % 256 == 0 && N % 128 == 0 && M / 256 == 32) {
    unsigned short* Abf = (unsigned short*)d_ws;
    unsigned short* Bbf = Abf + (size_t)N * D;
    float* y2 = (float*)(Bbf + (size_t)M * D);
    float* cand_s = y2 + M;
    int* cand_i = (int*)(cand_s + (size_t)N * 256);

    convert_all_kernel<<<N + M, 256, 0, stream>>>(A, Bm, Abf, Bbf, y2, N);
    dim3 g(M / 256, N / 128);
    screen2_kernel<<<g, 256, 0, stream>>>(Abf, Bbf, y2, cand_s, cand_i);
    finalize3_kernel<<<N / 4, 256, 0, stream>>>(A, Bm, y2, cand_s, cand_i,
                                                (float*)d_out);
  } else {
    float* y2 = (float*)d_ws;
    float* cand_s = y2 + M;
    int* cand_i = (int*)(cand_s + (size_t)N * 64);
    rownorm_kernel<<<M, 256, 0, stream>>>(Bm, y2);
    dim3 gridB(M / 1024, N / 64);
    knn_chunk_kernel<<<gridB, 256, 0, stream>>>(A, Bm, y2, cand_s, cand_i);
    finalize_kernel<<<N, 256, 0, stream>>>(A, Bm, cand_s, cand_i, (float*)d_out, M / 1024);
  }
}

// Round 5
// 377.040 us; speedup vs baseline: 1.0525x; 1.0101x over previous
//
#include <hip/hip_runtime.h>

// KNN (K=8) + inverse-distance-weighted average, MFMA screening version.
// data1: [N=4096, D=1024] fp32, data2: [M=8192, D=1024] fp32, out: [N, D] fp32.
//
// Fast path:
//  1) convert_all: A -> bf16; B -> bf16 fused with y2[m]=||B[m]||^2
//  2) screen3: bf16 MFMA GEMM, 128x256 tile, SWAPPED operands so C/D layout is
//     row-per-lane (lane&15 = A-row, (lane>>4)*4+reg = B-col). Epilogue is
//     barrier-free: per-lane insertion top-8 (32 cands) + shfl bitonic merge
//     of the 4 lanes sharing a row. 16 cands/row/block -> 512 cands/row.
//  3) finalize3: wave-per-row; 512 cands -> approx top-16 (64-bit key shfl
//     argmin) -> EXACT fp32 rescore -> top-8 by (d2, idx) ->
//     w = 1/(sqrt(max(d2,1e-12))+0.1) -> weighted gather.
// Fallback (small ws): round-1 pure-fp32 path (verified correct).

typedef short bf16x8 __attribute__((ext_vector_type(8)));
typedef float f32x4 __attribute__((ext_vector_type(4)));

#define SENTINEL 1e30f
#define BKK 32

static __device__ __forceinline__ unsigned short f2bf(float f) {
  unsigned u = __float_as_uint(f);
  return (unsigned short)((u + 0x7fffu + ((u >> 16) & 1u)) >> 16);
}

// ---------------- fast path kernels ----------------
// grid: N + M blocks. bid < N: convert A row. else: convert B row + norm.
__global__ __launch_bounds__(256) void convert_all_kernel(
    const float* __restrict__ A, const float* __restrict__ B,
    unsigned short* __restrict__ Abf, unsigned short* __restrict__ Bbf,
    float* __restrict__ y2, int N) {
  const int bid = blockIdx.x;
  const int tid = threadIdx.x;
  if (bid < N) {
    const float4 v = ((const float4*)&A[(size_t)bid * 1024])[tid];
    ushort4 o;
    o.x = f2bf(v.x); o.y = f2bf(v.y); o.z = f2bf(v.z); o.w = f2bf(v.w);
    ((ushort4*)&Abf[(size_t)bid * 1024])[tid] = o;
  } else {
    const int m = bid - N;
    __shared__ float red[256];
    const float4 v = ((const float4*)&B[(size_t)m * 1024])[tid];
    ushort4 o;
    o.x = f2bf(v.x); o.y = f2bf(v.y); o.z = f2bf(v.z); o.w = f2bf(v.w);
    ((ushort4*)&Bbf[(size_t)m * 1024])[tid] = o;
    red[tid] = v.x * v.x + v.y * v.y + v.z * v.z + v.w * v.w;
    __syncthreads();
    for (int s = 128; s > 0; s >>= 1) {
      if (tid < s) red[tid] += red[tid + s];
      __syncthreads();
    }
    if (tid == 0) y2[m] = red[0];
  }
}

// ascending compare-exchange on (s, i) register pairs
#define CAS(sa, ia, sb, ib)                         \
  do {                                              \
    if ((sa) > (sb)) {                              \
      const float _t = (sa); (sa) = (sb); (sb) = _t;\
      const int _u = (ia); (ia) = (ib); (ib) = _u;  \
    }                                               \
  } while (0)

// grid: (M/256, N/128), 256 threads = 4 waves (2 row-halves x 2 col-halves).
// Per wave: 64 rows x 128 cols, 4x8 fragments of 16x16x32 bf16 MFMA,
// operands SWAPPED so each lane's acc holds 4 cols of one row per fragment.
// LDS XOR swizzle: k-chunk kc of row r stored at column kc ^ ((r>>1)&3).
__global__ __launch_bounds__(256, 2) void screen3_kernel(
    const unsigned short* __restrict__ Abf, const unsigned short* __restrict__ Bbf,
    const float* __restrict__ y2g,
    float* __restrict__ cand_s, int* __restrict__ cand_i) {
  __shared__ unsigned short As[128 * 32];  // 8 KB
  __shared__ unsigned short Bs[256 * 32];  // 16 KB
  __shared__ float y2sh[256];

  const int tid = threadIdx.x;
  const int w = tid >> 6;
  const int lane = tid & 63;
  const int wr = w >> 1, wc = w & 1;
  const int r0 = blockIdx.y * 128;
  const int c0 = blockIdx.x * 256;

  y2sh[tid] = y2g[c0 + tid];

  // staging: lane -> LDS slot (16 rows per glds), swizzle on global source
  const int srow = lane >> 2;                          // 0..15
  const int sofs = ((lane & 3) ^ ((lane >> 3) & 3)) * 8;

  // fragment reads: LDS col = kc ^ ((row>>1)&3), kc = lane>>4
  const int frowA = wr * 64 + (lane & 15);
  const int frowB = wc * 128 + (lane & 15);
  const int fofs = ((lane >> 4) ^ ((lane >> 1) & 3)) * 8;

  f32x4 acc[4][8];
#pragma unroll
  for (int fi = 0; fi < 4; ++fi)
#pragma unroll
    for (int fj = 0; fj < 8; ++fj) {
      f32x4 z = {0.f, 0.f, 0.f, 0.f};
      acc[fi][fj] = z;
    }

  for (int k0 = 0; k0 < 1024; k0 += BKK) {
    const unsigned short* gA =
        Abf + (size_t)(r0 + w * 32 + srow) * 1024 + k0 + sofs;
    const unsigned short* gB =
        Bbf + (size_t)(c0 + w * 64 + srow) * 1024 + k0 + sofs;
    __syncthreads();  // previous iteration's fragment reads complete
    __builtin_amdgcn_global_load_lds(
        (const __attribute__((address_space(1))) void*)gA,
        (__attribute__((address_space(3))) void*)&As[(w * 32) * 32], 16, 0, 0);
    __builtin_amdgcn_global_load_lds(
        (const __attribute__((address_space(1))) void*)(gA + (size_t)16 * 1024),
        (__attribute__((address_space(3))) void*)&As[(w * 32 + 16) * 32], 16, 0, 0);
#pragma unroll
    for (int l = 0; l < 4; ++l)
      __builtin_amdgcn_global_load_lds(
          (const __attribute__((address_space(1))) void*)(gB + (size_t)(16 * l) * 1024),
          (__attribute__((address_space(3))) void*)&Bs[(w * 64 + 16 * l) * 32], 16, 0, 0);
    __syncthreads();  // staged data visible

    bf16x8 af[4], bfr[8];
#pragma unroll
    for (int fi = 0; fi < 4; ++fi)
      af[fi] = *(const bf16x8*)&As[(frowA + fi * 16) * 32 + fofs];
#pragma unroll
    for (int fj = 0; fj < 8; ++fj)
      bfr[fj] = *(const bf16x8*)&Bs[(frowB + fj * 16) * 32 + fofs];
    // SWAPPED: B-frag as A-operand, A-frag as B-operand ->
    // D[m=B-col][n=A-row]; lane&15 = A-row, (lane>>4)*4+reg = B-col.
#pragma unroll
    for (int fi = 0; fi < 4; ++fi)
#pragma unroll
      for (int fj = 0; fj < 8; ++fj)
        acc[fi][fj] = __builtin_amdgcn_mfma_f32_16x16x32_bf16(
            bfr[fj], af[fi], acc[fi][fj], 0, 0, 0);
  }

  // barrier-free epilogue. Lane's candidates: row = r0+wr*64+fi*16+(lane&15),
  // col = c0 + wc*128 + fj*16 + (lane>>4)*4 + reg.
  const int cgrp = (lane >> 4) * 4;
  float4 y2v[8];
#pragma unroll
  for (int fj = 0; fj < 8; ++fj)
    y2v[fj] = *(const float4*)&y2sh[wc * 128 + fj * 16 + cgrp];

#pragma unroll
  for (int fi = 0; fi < 4; ++fi) {
    float ls[8];
    int li[8];
#pragma unroll
    for (int j = 0; j < 8; ++j) { ls[j] = SENTINEL; li[j] = 0x7fffffff; }
    const int cb = c0 + wc * 128 + cgrp;
#pragma unroll
    for (int fj = 0; fj < 8; ++fj) {
#pragma unroll
      for (int reg = 0; reg < 4; ++reg) {
        const float s = y2v[fj][reg] - 2.0f * acc[fi][fj][reg];
        if (s < ls[7]) {
          ls[7] = s; li[7] = cb + fj * 16 + reg;
#pragma unroll
          for (int j = 7; j > 0; --j) {
            if (ls[j] < ls[j - 1]) {
              const float t = ls[j]; ls[j] = ls[j - 1]; ls[j - 1] = t;
              const int u = li[j]; li[j] = li[j - 1]; li[j - 1] = u;
            }
          }
        }
      }
    }
    // merge sorted 8-lists across the 4 lanes sharing this row (lane^16, ^32)
#pragma unroll
    for (int off = 16; off <= 32; off <<= 1) {
      float rs[8];
      int ri[8];
#pragma unroll
      for (int j = 0; j < 8; ++j) {
        rs[j] = __shfl_xor(ls[j], off, 64);
        ri[j] = __shfl_xor(li[j], off, 64);
      }
      // half-cleaner: 8 smallest of the 16 = min(ls[i], rs[7-i]), bitonic
      float ms[8];
      int mi_[8];
#pragma unroll
      for (int i = 0; i < 8; ++i) {
        const bool t = ls[i] < rs[7 - i];
        ms[i] = t ? ls[i] : rs[7 - i];
        mi_[i] = t ? li[i] : ri[7 - i];
      }
      // bitonic sort-8 (ascending): stages d=4,2,1
      CAS(ms[0], mi_[0], ms[4], mi_[4]);
      CAS(ms[1], mi_[1], ms[5], mi_[5]);
      CAS(ms[2], mi_[2], ms[6], mi_[6]);
      CAS(ms[3], mi_[3], ms[7], mi_[7]);
      CAS(ms[0], mi_[0], ms[2], mi_[2]);
      CAS(ms[1], mi_[1], ms[3], mi_[3]);
      CAS(ms[4], mi_[4], ms[6], mi_[6]);
      CAS(ms[5], mi_[5], ms[7], mi_[7]);
      CAS(ms[0], mi_[0], ms[1], mi_[1]);
      CAS(ms[2], mi_[2], ms[3], mi_[3]);
      CAS(ms[4], mi_[4], ms[5], mi_[5]);
      CAS(ms[6], mi_[6], ms[7], mi_[7]);
#pragma unroll
      for (int j = 0; j < 8; ++j) { ls[j] = ms[j]; li[j] = mi_[j]; }
    }
    if ((lane >> 4) == 0) {  // lanes 0..15 hold the merged per-row top-8
      const int row = r0 + wr * 64 + fi * 16 + lane;
      const size_t base = ((size_t)row * 64 + wc * 32 + blockIdx.x) * 8;
#pragma unroll
      for (int j = 0; j < 8; ++j) {
        cand_s[base + j] = ls[j];
        cand_i[base + j] = li[j];
      }
    }
  }
}

// wave-per-row: grid N/4 blocks x 256 threads. 512 cand -> top-16 approx ->
// exact fp32 rescore -> top-8 -> weighted gather. Lane owns elems lane*16..+15.
__global__ __launch_bounds__(256) void finalize3_kernel(
    const float* __restrict__ A, const float* __restrict__ B,
    const float* __restrict__ y2g,
    const float* __restrict__ cand_s, const int* __restrict__ cand_i,
    float* __restrict__ out) {
  const int tid = threadIdx.x;
  const int w = tid >> 6;
  const int lane = tid & 63;
  const int n = blockIdx.x * 4 + w;
  __shared__ int mi[4][512];

  unsigned long long key[8];
#pragma unroll
  for (int i = 0; i < 8; ++i) {
    const int slot = lane + 64 * i;
    const float s = cand_s[(size_t)n * 512 + slot];
    mi[w][slot] = cand_i[(size_t)n * 512 + slot];
    unsigned u = __float_as_uint(s);
    u = (u & 0x80000000u) ? ~u : (u | 0x80000000u);
    key[i] = ((unsigned long long)u << 32) | (unsigned)slot;
  }
  __syncthreads();

  int ci[16];
  for (int r = 0; r < 16; ++r) {
    unsigned long long kb = key[0];
#pragma unroll
    for (int i = 1; i < 8; ++i) kb = key[i] < kb ? key[i] : kb;
#pragma unroll
    for (int off = 32; off >= 1; off >>= 1) {
      const unsigned long long o = __shfl_xor(kb, off, 64);
      kb = o < kb ? o : kb;
    }
    const int slot = (int)(kb & 0xffffffffu);
    ci[r] = mi[w][slot];
#pragma unroll
    for (int i = 0; i < 8; ++i)
      if (slot == lane + 64 * i) key[i] = ~0ull;
  }

  // exact fp32 partial dots; lane covers 16 contiguous elements
  const float4* Arow = (const float4*)&A[(size_t)n * 1024];
  const float4 a0 = Arow[lane * 4 + 0];
  const float4 a1 = Arow[lane * 4 + 1];
  const float4 a2 = Arow[lane * 4 + 2];
  const float4 a3 = Arow[lane * 4 + 3];
  float part[17];
  part[16] = a0.x * a0.x + a0.y * a0.y + a0.z * a0.z + a0.w * a0.w +
             a1.x * a1.x + a1.y * a1.y + a1.z * a1.z + a1.w * a1.w +
             a2.x * a2.x + a2.y * a2.y + a2.z * a2.z + a2.w * a2.w +
             a3.x * a3.x + a3.y * a3.y + a3.z * a3.z + a3.w * a3.w;
#pragma unroll
  for (int j = 0; j < 16; ++j) {
    const float4* Brow = (const float4*)&B[(size_t)ci[j] * 1024];
    const float4 b0 = Brow[lane * 4 + 0];
    const float4 b1 = Brow[lane * 4 + 1];
    const float4 b2 = Brow[lane * 4 + 2];
    const float4 b3 = Brow[lane * 4 + 3];
    part[j] = a0.x * b0.x + a0.y * b0.y + a0.z * b0.z + a0.w * b0.w +
              a1.x * b1.x + a1.y * b1.y + a1.z * b1.z + a1.w * b1.w +
              a2.x * b2.x + a2.y * b2.y + a2.z * b2.z + a2.w * b2.w +
              a3.x * b3.x + a3.y * b3.y + a3.z * b3.z + a3.w * b3.w;
  }
#pragma unroll
  for (int r = 0; r < 17; ++r) {
#pragma unroll
    for (int off = 32; off >= 1; off >>= 1) part[r] += __shfl_xor(part[r], off, 64);
  }

  // all lanes hold identical totals: redundant uniform selection
  const float x2 = part[16];
  float d2v[16];
  bool used[16];
#pragma unroll
  for (int j = 0; j < 16; ++j) {
    d2v[j] = x2 + y2g[ci[j]] - 2.0f * part[j];
    used[j] = false;
  }
  float wk[8];
  int wi[8];
  float wsum = 0.0f;
  for (int k = 0; k < 8; ++k) {
    float bd = SENTINEL;
    int bi = 0x7fffffff, bslot = 0;
#pragma unroll
    for (int j = 0; j < 16; ++j) {
      if (used[j]) continue;
      const float d2 = d2v[j];
      if (d2 < bd || (d2 == bd && ci[j] < bi)) { bd = d2; bi = ci[j]; bslot = j; }
    }
    used[bslot] = true;
    const float d2c = fmaxf(bd, 1e-12f);
    const float wv = 1.0f / (sqrtf(d2c) + 0.1f);
    wk[k] = wv; wi[k] = bi; wsum += wv;
  }
  const float inv = 1.0f / wsum;

  float4 o0 = {0, 0, 0, 0}, o1 = {0, 0, 0, 0}, o2 = {0, 0, 0, 0}, o3 = {0, 0, 0, 0};
#pragma unroll
  for (int k = 0; k < 8; ++k) {
    const float wv = wk[k];
    const float4* Brow = (const float4*)&B[(size_t)wi[k] * 1024];
    const float4 b0 = Brow[lane * 4 + 0];
    const float4 b1 = Brow[lane * 4 + 1];
    const float4 b2 = Brow[lane * 4 + 2];
    const float4 b3 = Brow[lane * 4 + 3];
    o0.x += wv * b0.x; o0.y += wv * b0.y; o0.z += wv * b0.z; o0.w += wv * b0.w;
    o1.x += wv * b1.x; o1.y += wv * b1.y; o1.z += wv * b1.z; o1.w += wv * b1.w;
    o2.x += wv * b2.x; o2.y += wv * b2.y; o2.z += wv * b2.z; o2.w += wv * b2.w;
    o3.x += wv * b3.x; o3.y += wv * b3.y; o3.z += wv * b3.z; o3.w += wv * b3.w;
  }
  float4* Orow = (float4*)&out[(size_t)n * 1024];
  o0.x *= inv; o0.y *= inv; o0.z *= inv; o0.w *= inv;
  o1.x *= inv; o1.y *= inv; o1.z *= inv; o1.w *= inv;
  o2.x *= inv; o2.y *= inv; o2.z *= inv; o2.w *= inv;
  o3.x *= inv; o3.y *= inv; o3.z *= inv; o3.w *= inv;
  Orow[lane * 4 + 0] = o0;
  Orow[lane * 4 + 1] = o1;
  Orow[lane * 4 + 2] = o2;
  Orow[lane * 4 + 3] = o3;
}

// ---------------- fallback path (round-1, verified) ----------------
__global__ __launch_bounds__(256) void rownorm_kernel(
    const float* __restrict__ B, float* __restrict__ y2) {
  const int m = blockIdx.x;
  const int tid = threadIdx.x;
  __shared__ float red[256];
  const float4 v = *(const float4*)&B[(size_t)m * 1024 + tid * 4];
  red[tid] = v.x * v.x + v.y * v.y + v.z * v.z + v.w * v.w;
  __syncthreads();
  for (int s = 128; s > 0; s >>= 1) {
    if (tid < s) red[tid] += red[tid + s];
    __syncthreads();
  }
  if (tid == 0) y2[m] = red[0];
}

__global__ __launch_bounds__(256) void knn_chunk_kernel(
    const float* __restrict__ A, const float* __restrict__ B,
    const float* __restrict__ y2g,
    float* __restrict__ cand_s, int* __restrict__ cand_i) {
  __shared__ float As[BKK][68];
  __shared__ float Bs[BKK][68];
  __shared__ float Sc[64][65];

  const int tid = threadIdx.x;
  const int tx = tid & 15;
  const int ty = tid >> 4;
  const int r0 = blockIdx.y * 64;
  const int c0 = blockIdx.x * 1024;
  const int lrow = tid >> 3;
  const int lk = (tid & 7) * 4;

  float top_s[8];
  int top_i[8];
#pragma unroll
  for (int j = 0; j < 8; ++j) { top_s[j] = SENTINEL; top_i[j] = 0x7fffffff; }

  for (int tile = 0; tile < 16; ++tile) {
    const int cbase = c0 + tile * 64;
    float acc[4][4];
#pragma unroll
    for (int i = 0; i < 4; ++i)
#pragma unroll
      for (int j = 0; j < 4; ++j) acc[i][j] = 0.0f;

    for (int k0 = 0; k0 < 1024; k0 += BKK) {
      const float4 a0 = *(const float4*)&A[(size_t)(r0 + lrow) * 1024 + k0 + lk];
      const float4 a1 = *(const float4*)&A[(size_t)(r0 + lrow + 32) * 1024 + k0 + lk];
      const float4 b0 = *(const float4*)&B[(size_t)(cbase + lrow) * 1024 + k0 + lk];
      const float4 b1 = *(const float4*)&B[(size_t)(cbase + lrow + 32) * 1024 + k0 + lk];
      __syncthreads();
      As[lk + 0][lrow] = a0.x; As[lk + 1][lrow] = a0.y;
      As[lk + 2][lrow] = a0.z; As[lk + 3][lrow] = a0.w;
      As[lk + 0][lrow + 32] = a1.x; As[lk + 1][lrow + 32] = a1.y;
      As[lk + 2][lrow + 32] = a1.z; As[lk + 3][lrow + 32] = a1.w;
      Bs[lk + 0][lrow] = b0.x; Bs[lk + 1][lrow] = b0.y;
      Bs[lk + 2][lrow] = b0.z; Bs[lk + 3][lrow] = b0.w;
      Bs[lk + 0][lrow + 32] = b1.x; Bs[lk + 1][lrow + 32] = b1.y;
      Bs[lk + 2][lrow + 32] = b1.z; Bs[lk + 3][lrow + 32] = b1.w;
      __syncthreads();
#pragma unroll
      for (int kk = 0; kk < BKK; ++kk) {
        const float4 av = *(const float4*)&As[kk][ty * 4];
        const float4 bv = *(const float4*)&Bs[kk][tx * 4];
        acc[0][0] += av.x * bv.x; acc[0][1] += av.x * bv.y;
        acc[0][2] += av.x * bv.z; acc[0][3] += av.x * bv.w;
        acc[1][0] += av.y * bv.x; acc[1][1] += av.y * bv.y;
        acc[1][2] += av.y * bv.z; acc[1][3] += av.y * bv.w;
        acc[2][0] += av.z * bv.x; acc[2][1] += av.z * bv.y;
        acc[2][2] += av.z * bv.z; acc[2][3] += av.z * bv.w;
        acc[3][0] += av.w * bv.x; acc[3][1] += av.w * bv.y;
        acc[3][2] += av.w * bv.z; acc[3][3] += av.w * bv.w;
      }
    }
#pragma unroll
    for (int i = 0; i < 4; ++i) {
      const int row = ty * 4 + i;
#pragma unroll
      for (int j = 0; j < 4; ++j) {
        const int col = tx * 4 + j;
        Sc[row][col] = y2g[cbase + col] - 2.0f * acc[i][j];
      }
    }
    __syncthreads();
    if (tid < 64) {
      for (int c = 0; c < 64; ++c) {
        const float s = Sc[tid][c];
        if (s < top_s[7]) {
          top_s[7] = s; top_i[7] = cbase + c;
#pragma unroll
          for (int j = 7; j > 0; --j) {
            if (top_s[j] < top_s[j - 1]) {
              const float tss = top_s[j]; top_s[j] = top_s[j - 1]; top_s[j - 1] = tss;
              const int tii = top_i[j]; top_i[j] = top_i[j - 1]; top_i[j - 1] = tii;
            }
          }
        }
      }
    }
  }

  if (tid < 64) {
    const int n = r0 + tid;
    const int base = (n * gridDim.x + blockIdx.x) * 8;
#pragma unroll
    for (int j = 0; j < 8; ++j) {
      cand_s[base + j] = top_s[j];
      cand_i[base + j] = top_i[j];
    }
  }
}

__global__ __launch_bounds__(256) void finalize_kernel(
    const float* __restrict__ A, const float* __restrict__ B,
    const float* __restrict__ cand_s, const int* __restrict__ cand_i,
    float* __restrict__ out, int nchunks) {
  const int n = blockIdx.x;
  const int tid = threadIdx.x;
  __shared__ float red[256];
  __shared__ float ls[64];
  __shared__ int li[64];
  __shared__ float wsh2[8];
  __shared__ int wid[8];
  __shared__ float wsum_sh;

  const int ncand = nchunks * 8;
  const float4 a = *(const float4*)&A[(size_t)n * 1024 + tid * 4];
  red[tid] = a.x * a.x + a.y * a.y + a.z * a.z + a.w * a.w;
  if (tid < ncand) {
    ls[tid] = cand_s[n * ncand + tid];
    li[tid] = cand_i[n * ncand + tid];
  }
  __syncthreads();
  for (int s = 128; s > 0; s >>= 1) {
    if (tid < s) red[tid] += red[tid + s];
    __syncthreads();
  }
  if (tid == 0) {
    const float x2 = red[0];
    float wsum = 0.0f;
    for (int j = 0; j < 8; ++j) {
      float bs = SENTINEL;
      int bi = 0x7fffffff;
      int bp = 0;
      for (int c = 0; c < ncand; ++c) {
        const float s_ = ls[c];
        const int i_ = li[c];
        if (s_ < bs || (s_ == bs && i_ < bi)) { bs = s_; bi = i_; bp = c; }
      }
      ls[bp] = SENTINEL; li[bp] = 0x7fffffff;
      float d2 = x2 + bs;
      d2 = fmaxf(d2, 1e-12f);
      const float wkk = 1.0f / (sqrtf(d2) + 0.1f);
      wsh2[j] = wkk; wid[j] = bi;
      wsum += wkk;
    }
    wsum_sh = wsum;
  }
  __syncthreads();
  const float inv = 1.0f / wsum_sh;
  float ox = 0.0f, oy = 0.0f, oz = 0.0f, ow = 0.0f;
#pragma unroll
  for (int j = 0; j < 8; ++j) {
    const float wkk = wsh2[j];
    const float4 v = *(const float4*)&B[(size_t)wid[j] * 1024 + tid * 4];
    ox += wkk * v.x; oy += wkk * v.y; oz += wkk * v.z; ow += wkk * v.w;
  }
  float4 o;
  o.x = ox * inv; o.y = oy * inv; o.z = oz * inv; o.w = ow * inv;
  *(float4*)&out[(size_t)n * 1024 + tid * 4] = o;
}

extern "C" void kernel_launch(void* const* d_in, const int* in_sizes, int n_in,
                              void* d_out, int out_size, void* d_ws, size_t ws_size,
                              hipStream_t stream) {
  const float* A = (const float*)d_in[0];
  const float* Bm = (const float*)d_in[1];
  const int D = 1024;
  const int N = in_sizes[0] / D;  // 4096
  const int M = in_sizes[1] / D;  // 8192

  const size_t needA = (size_t)N * D * 2;
  const size_t needB = (size_t)M * D * 2;
  const size_t needC = (size_t)N * 512 * 4;  // cand_s (== cand_i)
  const size_t need = needA + needB + (size_t)M * 4 + 2 * needC;

  if (ws_size >= need && M == 8192 && N % 128 == 0) {
    unsigned short* Abf = (unsigned short*)d_ws;
    unsigned short* Bbf = Abf + (size_t)N * D;
    float* y2 = (float*)(Bbf + (size_t)M * D);
    float* cand_s = y2 + M;
    int* cand_i = (int*)(cand_s + (size_t)N * 512);

    convert_all_kernel<<<N + M, 256, 0, stream>>>(A, Bm, Abf, Bbf, y2, N);
    dim3 g(M / 256, N / 128);
    screen3_kernel<<<g, 256, 0, stream>>>(Abf, Bbf, y2, cand_s, cand_i);
    finalize3_kernel<<<N / 4, 256, 0, stream>>>(A, Bm, y2, cand_s, cand_i,
                                                (float*)d_out);
  } else {
    float* y2 = (float*)d_ws;
    float* cand_s = y2 + M;
    int* cand_i = (int*)(cand_s + (size_t)N * 64);
    rownorm_kernel<<<M, 256, 0, stream>>>(Bm, y2);
    dim3 gridB(M / 1024, N / 64);
    knn_chunk_kernel<<<gridB, 256, 0, stream>>>(A, Bm, y2, cand_s, cand_i);
    finalize_kernel<<<N, 256, 0, stream>>>(A, Bm, cand_s, cand_i, (float*)d_out, M / 1024);
  }
}

// Round 6
// 345.404 us; speedup vs baseline: 1.1489x; 1.0916x over previous
//
#include <hip/hip_runtime.h>

// KNN (K=8) + inverse-distance-weighted average, MFMA screening version.
// data1: [N=4096, D=1024] fp32, data2: [M=8192, D=1024] fp32, out: [N, D] fp32.
//
// Fast path:
//  1) convert_all: A -> bf16; B -> bf16 fused with y2[m]=||B[m]||^2
//  2) screen4: bf16 MFMA GEMM, 128x256 tile, 2 col-chunks per block
//     (grid 512 = one full-occupancy round at 2 blocks/CU), SWAPPED operands
//     so C/D is row-per-lane; barrier-free epilogue (per-lane insertion top-8
//     + shfl bitonic merge). 16 cands/row/chunk -> 512 cands/row.
//  3) finalize4: 2 waves per row; 512 cands -> approx top-12 (64-bit key shfl
//     argmin) -> EXACT fp32 rescore (position-interleaved, 12 loads in
//     flight) -> top-8 by (d2, idx) -> w = 1/(sqrt(max(d2,1e-12))+0.1) ->
//     weighted gather.
// Fallback (small ws): round-1 pure-fp32 path (verified correct).

typedef short bf16x8 __attribute__((ext_vector_type(8)));
typedef float f32x4 __attribute__((ext_vector_type(4)));

#define SENTINEL 1e30f
#define BKK 32

static __device__ __forceinline__ unsigned short f2bf(float f) {
  unsigned u = __float_as_uint(f);
  return (unsigned short)((u + 0x7fffu + ((u >> 16) & 1u)) >> 16);
}

// ---------------- fast path kernels ----------------
// grid: N + M blocks. bid < N: convert A row. else: convert B row + norm.
__global__ __launch_bounds__(256) void convert_all_kernel(
    const float* __restrict__ A, const float* __restrict__ B,
    unsigned short* __restrict__ Abf, unsigned short* __restrict__ Bbf,
    float* __restrict__ y2, int N) {
  const int bid = blockIdx.x;
  const int tid = threadIdx.x;
  if (bid < N) {
    const float4 v = ((const float4*)&A[(size_t)bid * 1024])[tid];
    ushort4 o;
    o.x = f2bf(v.x); o.y = f2bf(v.y); o.z = f2bf(v.z); o.w = f2bf(v.w);
    ((ushort4*)&Abf[(size_t)bid * 1024])[tid] = o;
  } else {
    const int m = bid - N;
    __shared__ float red[256];
    const float4 v = ((const float4*)&B[(size_t)m * 1024])[tid];
    ushort4 o;
    o.x = f2bf(v.x); o.y = f2bf(v.y); o.z = f2bf(v.z); o.w = f2bf(v.w);
    ((ushort4*)&Bbf[(size_t)m * 1024])[tid] = o;
    red[tid] = v.x * v.x + v.y * v.y + v.z * v.z + v.w * v.w;
    __syncthreads();
    for (int s = 128; s > 0; s >>= 1) {
      if (tid < s) red[tid] += red[tid + s];
      __syncthreads();
    }
    if (tid == 0) y2[m] = red[0];
  }
}

// ascending compare-exchange on (s, i) register pairs
#define CAS(sa, ia, sb, ib)                         \
  do {                                              \
    if ((sa) > (sb)) {                              \
      const float _t = (sa); (sa) = (sb); (sb) = _t;\
      const int _u = (ia); (ia) = (ib); (ib) = _u;  \
    }                                               \
  } while (0)

// grid: (M/512, N/128), 256 threads = 4 waves (2 row-halves x 2 col-halves).
// Each block processes 2 sequential 256-col chunks (one occupancy round:
// 512 blocks = 2 blocks/CU x 256 CU). Per chunk: 128x256 tile, acc[4][8],
// SWAPPED MFMA operands -> row-per-lane C/D; barrier-free epilogue.
// LDS XOR swizzle: k-chunk kc of row r stored at column kc ^ ((r>>1)&3).
__global__ __launch_bounds__(256, 2) void screen4_kernel(
    const unsigned short* __restrict__ Abf, const unsigned short* __restrict__ Bbf,
    const float* __restrict__ y2g,
    float* __restrict__ cand_s, int* __restrict__ cand_i) {
  __shared__ unsigned short As[128 * 32];  // 8 KB
  __shared__ unsigned short Bs[256 * 32];  // 16 KB
  __shared__ float y2sh[256];

  const int tid = threadIdx.x;
  const int w = tid >> 6;
  const int lane = tid & 63;
  const int wr = w >> 1, wc = w & 1;
  const int r0 = blockIdx.y * 128;

  // staging: lane -> LDS slot (16 rows per glds), swizzle on global source
  const int srow = lane >> 2;                          // 0..15
  const int sofs = ((lane & 3) ^ ((lane >> 3) & 3)) * 8;

  // fragment reads: LDS col = kc ^ ((row>>1)&3), kc = lane>>4
  const int frowA = wr * 64 + (lane & 15);
  const int frowB = wc * 128 + (lane & 15);
  const int fofs = ((lane >> 4) ^ ((lane >> 1) & 3)) * 8;
  const int cgrp = (lane >> 4) * 4;

  for (int chunk = 0; chunk < 2; ++chunk) {
    const int c0 = blockIdx.x * 512 + chunk * 256;
    __syncthreads();  // chunk-1 epilogue y2sh reads done before overwrite
    y2sh[tid] = y2g[c0 + tid];

    f32x4 acc[4][8];
#pragma unroll
    for (int fi = 0; fi < 4; ++fi)
#pragma unroll
      for (int fj = 0; fj < 8; ++fj) {
        f32x4 z = {0.f, 0.f, 0.f, 0.f};
        acc[fi][fj] = z;
      }

    for (int k0 = 0; k0 < 1024; k0 += BKK) {
      const unsigned short* gA =
          Abf + (size_t)(r0 + w * 32 + srow) * 1024 + k0 + sofs;
      const unsigned short* gB =
          Bbf + (size_t)(c0 + w * 64 + srow) * 1024 + k0 + sofs;
      __syncthreads();  // previous iteration's fragment reads complete
      __builtin_amdgcn_global_load_lds(
          (const __attribute__((address_space(1))) void*)gA,
          (__attribute__((address_space(3))) void*)&As[(w * 32) * 32], 16, 0, 0);
      __builtin_amdgcn_global_load_lds(
          (const __attribute__((address_space(1))) void*)(gA + (size_t)16 * 1024),
          (__attribute__((address_space(3))) void*)&As[(w * 32 + 16) * 32], 16, 0, 0);
#pragma unroll
      for (int l = 0; l < 4; ++l)
        __builtin_amdgcn_global_load_lds(
            (const __attribute__((address_space(1))) void*)(gB + (size_t)(16 * l) * 1024),
            (__attribute__((address_space(3))) void*)&Bs[(w * 64 + 16 * l) * 32], 16, 0, 0);
      __syncthreads();  // staged data visible

      bf16x8 af[4], bfr[8];
#pragma unroll
      for (int fi = 0; fi < 4; ++fi)
        af[fi] = *(const bf16x8*)&As[(frowA + fi * 16) * 32 + fofs];
#pragma unroll
      for (int fj = 0; fj < 8; ++fj)
        bfr[fj] = *(const bf16x8*)&Bs[(frowB + fj * 16) * 32 + fofs];
      // SWAPPED: B-frag as A-operand, A-frag as B-operand ->
      // lane&15 = A-row, (lane>>4)*4+reg = B-col.
#pragma unroll
      for (int fi = 0; fi < 4; ++fi)
#pragma unroll
        for (int fj = 0; fj < 8; ++fj)
          acc[fi][fj] = __builtin_amdgcn_mfma_f32_16x16x32_bf16(
              bfr[fj], af[fi], acc[fi][fj], 0, 0, 0);
    }

    // barrier-free epilogue. Lane's cands: row = r0+wr*64+fi*16+(lane&15),
    // col = c0 + wc*128 + fj*16 + cgrp + reg.
    float4 y2v[8];
#pragma unroll
    for (int fj = 0; fj < 8; ++fj)
      y2v[fj] = *(const float4*)&y2sh[wc * 128 + fj * 16 + cgrp];

#pragma unroll
    for (int fi = 0; fi < 4; ++fi) {
      float ls[8];
      int li[8];
#pragma unroll
      for (int j = 0; j < 8; ++j) { ls[j] = SENTINEL; li[j] = 0x7fffffff; }
      const int cb = c0 + wc * 128 + cgrp;
#pragma unroll
      for (int fj = 0; fj < 8; ++fj) {
#pragma unroll
        for (int reg = 0; reg < 4; ++reg) {
          const float s = y2v[fj][reg] - 2.0f * acc[fi][fj][reg];
          if (s < ls[7]) {
            ls[7] = s; li[7] = cb + fj * 16 + reg;
#pragma unroll
            for (int j = 7; j > 0; --j) {
              if (ls[j] < ls[j - 1]) {
                const float t = ls[j]; ls[j] = ls[j - 1]; ls[j - 1] = t;
                const int u = li[j]; li[j] = li[j - 1]; li[j - 1] = u;
              }
            }
          }
        }
      }
      // merge sorted 8-lists across the 4 lanes sharing this row
#pragma unroll
      for (int off = 16; off <= 32; off <<= 1) {
        float rs[8];
        int ri[8];
#pragma unroll
        for (int j = 0; j < 8; ++j) {
          rs[j] = __shfl_xor(ls[j], off, 64);
          ri[j] = __shfl_xor(li[j], off, 64);
        }
        float ms[8];
        int mi_[8];
#pragma unroll
        for (int i = 0; i < 8; ++i) {
          const bool t = ls[i] < rs[7 - i];
          ms[i] = t ? ls[i] : rs[7 - i];
          mi_[i] = t ? li[i] : ri[7 - i];
        }
        CAS(ms[0], mi_[0], ms[4], mi_[4]);
        CAS(ms[1], mi_[1], ms[5], mi_[5]);
        CAS(ms[2], mi_[2], ms[6], mi_[6]);
        CAS(ms[3], mi_[3], ms[7], mi_[7]);
        CAS(ms[0], mi_[0], ms[2], mi_[2]);
        CAS(ms[1], mi_[1], ms[3], mi_[3]);
        CAS(ms[4], mi_[4], ms[6], mi_[6]);
        CAS(ms[5], mi_[5], ms[7], mi_[7]);
        CAS(ms[0], mi_[0], ms[1], mi_[1]);
        CAS(ms[2], mi_[2], ms[3], mi_[3]);
        CAS(ms[4], mi_[4], ms[5], mi_[5]);
        CAS(ms[6], mi_[6], ms[7], mi_[7]);
#pragma unroll
        for (int j = 0; j < 8; ++j) { ls[j] = ms[j]; li[j] = mi_[j]; }
      }
      if ((lane >> 4) == 0) {  // lanes 0..15 hold the merged per-row top-8
        const int row = r0 + wr * 64 + fi * 16 + lane;
        const size_t base =
            ((size_t)row * 64 + wc * 32 + blockIdx.x * 2 + chunk) * 8;
#pragma unroll
        for (int j = 0; j < 8; ++j) {
          cand_s[base + j] = ls[j];
          cand_i[base + j] = li[j];
        }
      }
    }
  }
}

// 2 waves per row: grid N/2 blocks x 256 threads (4 waves = 2 rows x 2
// wave-halves). 512 cand -> approx top-12 -> exact fp32 rescore
// (position-interleaved) -> top-8 -> weighted gather.
// Lane covers 8 contiguous elements: float4 idx = wh*128 + lane*2 + {0,1}.
__global__ __launch_bounds__(256) void finalize4_kernel(
    const float* __restrict__ A, const float* __restrict__ B,
    const float* __restrict__ y2g,
    const float* __restrict__ cand_s, const int* __restrict__ cand_i,
    float* __restrict__ out) {
  const int tid = threadIdx.x;
  const int w = tid >> 6;
  const int lane = tid & 63;
  const int rloc = w >> 1;  // row within block
  const int wh = w & 1;     // wave-half along D
  const int n = blockIdx.x * 2 + rloc;
  __shared__ int mi[2][512];
  __shared__ float comb[2][2][16];

  // both waves of a row build identical keys; wh==0 publishes indices
  unsigned long long key[8];
#pragma unroll
  for (int i = 0; i < 8; ++i) {
    const int slot = lane + 64 * i;
    const float s = cand_s[(size_t)n * 512 + slot];
    if (wh == 0) mi[rloc][slot] = cand_i[(size_t)n * 512 + slot];
    unsigned u = __float_as_uint(s);
    u = (u & 0x80000000u) ? ~u : (u | 0x80000000u);
    key[i] = ((unsigned long long)u << 32) | (unsigned)slot;
  }
  __syncthreads();

  int ci[12];
  for (int r = 0; r < 12; ++r) {
    unsigned long long kb = key[0];
#pragma unroll
    for (int i = 1; i < 8; ++i) kb = key[i] < kb ? key[i] : kb;
#pragma unroll
    for (int off = 32; off >= 1; off >>= 1) {
      const unsigned long long o = __shfl_xor(kb, off, 64);
      kb = o < kb ? o : kb;
    }
    const int slot = (int)(kb & 0xffffffffu);
    ci[r] = mi[rloc][slot];
#pragma unroll
    for (int i = 0; i < 8; ++i)
      if (slot == lane + 64 * i) key[i] = ~0ull;
  }

  // exact fp32 partial dots; position-interleaved for deep MLP
  const float4* Arow = (const float4*)&A[(size_t)n * 1024];
  const int fbase = wh * 128 + lane * 2;
  float4 a4[2];
  a4[0] = Arow[fbase];
  a4[1] = Arow[fbase + 1];
  float part[13];
#pragma unroll
  for (int r = 0; r < 13; ++r) part[r] = 0.0f;
  part[12] = a4[0].x * a4[0].x + a4[0].y * a4[0].y + a4[0].z * a4[0].z +
             a4[0].w * a4[0].w + a4[1].x * a4[1].x + a4[1].y * a4[1].y +
             a4[1].z * a4[1].z + a4[1].w * a4[1].w;
#pragma unroll
  for (int p = 0; p < 2; ++p) {
    float4 b[12];
#pragma unroll
    for (int j = 0; j < 12; ++j)
      b[j] = ((const float4*)&B[(size_t)ci[j] * 1024])[fbase + p];
#pragma unroll
    for (int j = 0; j < 12; ++j)
      part[j] += a4[p].x * b[j].x + a4[p].y * b[j].y + a4[p].z * b[j].z +
                 a4[p].w * b[j].w;
  }
#pragma unroll
  for (int r = 0; r < 13; ++r) {
#pragma unroll
    for (int off = 32; off >= 1; off >>= 1) part[r] += __shfl_xor(part[r], off, 64);
  }
  if (lane == 0) {
#pragma unroll
    for (int r = 0; r < 13; ++r) comb[rloc][wh][r] = part[r];
  }
  __syncthreads();
  float tot[13];
#pragma unroll
  for (int r = 0; r < 13; ++r) tot[r] = comb[rloc][0][r] + comb[rloc][1][r];

  // uniform redundant selection: top-8 by (d2, idx)
  const float x2 = tot[12];
  float d2v[12];
  bool used[12];
#pragma unroll
  for (int j = 0; j < 12; ++j) {
    d2v[j] = x2 + y2g[ci[j]] - 2.0f * tot[j];
    used[j] = false;
  }
  float wk[8];
  int wi[8];
  float wsum = 0.0f;
  for (int k = 0; k < 8; ++k) {
    float bd = SENTINEL;
    int bi = 0x7fffffff, bslot = 0;
#pragma unroll
    for (int j = 0; j < 12; ++j) {
      if (used[j]) continue;
      const float d2 = d2v[j];
      if (d2 < bd || (d2 == bd && ci[j] < bi)) { bd = d2; bi = ci[j]; bslot = j; }
    }
    used[bslot] = true;
    const float d2c = fmaxf(bd, 1e-12f);
    const float wv = 1.0f / (sqrtf(d2c) + 0.1f);
    wk[k] = wv; wi[k] = bi; wsum += wv;
  }
  const float inv = 1.0f / wsum;

  float4 o0 = {0, 0, 0, 0}, o1 = {0, 0, 0, 0};
#pragma unroll
  for (int k = 0; k < 8; ++k) {
    const float wv = wk[k];
    const float4* Brow = (const float4*)&B[(size_t)wi[k] * 1024];
    const float4 b0 = Brow[fbase];
    const float4 b1 = Brow[fbase + 1];
    o0.x += wv * b0.x; o0.y += wv * b0.y; o0.z += wv * b0.z; o0.w += wv * b0.w;
    o1.x += wv * b1.x; o1.y += wv * b1.y; o1.z += wv * b1.z; o1.w += wv * b1.w;
  }
  o0.x *= inv; o0.y *= inv; o0.z *= inv; o0.w *= inv;
  o1.x *= inv; o1.y *= inv; o1.z *= inv; o1.w *= inv;
  float4* Orow = (float4*)&out[(size_t)n * 1024];
  Orow[fbase] = o0;
  Orow[fbase + 1] = o1;
}

// ---------------- fallback path (round-1, verified) ----------------
__global__ __launch_bounds__(256) void rownorm_kernel(
    const float* __restrict__ B, float* __restrict__ y2) {
  const int m = blockIdx.x;
  const int tid = threadIdx.x;
  __shared__ float red[256];
  const float4 v = *(const float4*)&B[(size_t)m * 1024 + tid * 4];
  red[tid] = v.x * v.x + v.y * v.y + v.z * v.z + v.w * v.w;
  __syncthreads();
  for (int s = 128; s > 0; s >>= 1) {
    if (tid < s) red[tid] += red[tid + s];
    __syncthreads();
  }
  if (tid == 0) y2[m] = red[0];
}

__global__ __launch_bounds__(256) void knn_chunk_kernel(
    const float* __restrict__ A, const float* __restrict__ B,
    const float* __restrict__ y2g,
    float* __restrict__ cand_s, int* __restrict__ cand_i) {
  __shared__ float As[BKK][68];
  __shared__ float Bs[BKK][68];
  __shared__ float Sc[64][65];

  const int tid = threadIdx.x;
  const int tx = tid & 15;
  const int ty = tid >> 4;
  const int r0 = blockIdx.y * 64;
  const int c0 = blockIdx.x * 1024;
  const int lrow = tid >> 3;
  const int lk = (tid & 7) * 4;

  float top_s[8];
  int top_i[8];
#pragma unroll
  for (int j = 0; j < 8; ++j) { top_s[j] = SENTINEL; top_i[j] = 0x7fffffff; }

  for (int tile = 0; tile < 16; ++tile) {
    const int cbase = c0 + tile * 64;
    float acc[4][4];
#pragma unroll
    for (int i = 0; i < 4; ++i)
#pragma unroll
      for (int j = 0; j < 4; ++j) acc[i][j] = 0.0f;

    for (int k0 = 0; k0 < 1024; k0 += BKK) {
      const float4 a0 = *(const float4*)&A[(size_t)(r0 + lrow) * 1024 + k0 + lk];
      const float4 a1 = *(const float4*)&A[(size_t)(r0 + lrow + 32) * 1024 + k0 + lk];
      const float4 b0 = *(const float4*)&B[(size_t)(cbase + lrow) * 1024 + k0 + lk];
      const float4 b1 = *(const float4*)&B[(size_t)(cbase + lrow + 32) * 1024 + k0 + lk];
      __syncthreads();
      As[lk + 0][lrow] = a0.x; As[lk + 1][lrow] = a0.y;
      As[lk + 2][lrow] = a0.z; As[lk + 3][lrow] = a0.w;
      As[lk + 0][lrow + 32] = a1.x; As[lk + 1][lrow + 32] = a1.y;
      As[lk + 2][lrow + 32] = a1.z; As[lk + 3][lrow + 32] = a1.w;
      Bs[lk + 0][lrow] = b0.x; Bs[lk + 1][lrow] = b0.y;
      Bs[lk + 2][lrow] = b0.z; Bs[lk + 3][lrow] = b0.w;
      Bs[lk + 0][lrow + 32] = b1.x; Bs[lk + 1][lrow + 32] = b1.y;
      Bs[lk + 2][lrow + 32] = b1.z; Bs[lk + 3][lrow + 32] = b1.w;
      __syncthreads();
#pragma unroll
      for (int kk = 0; kk < BKK; ++kk) {
        const float4 av = *(const float4*)&As[kk][ty * 4];
        const float4 bv = *(const float4*)&Bs[kk][tx * 4];
        acc[0][0] += av.x * bv.x; acc[0][1] += av.x * bv.y;
        acc[0][2] += av.x * bv.z; acc[0][3] += av.x * bv.w;
        acc[1][0] += av.y * bv.x; acc[1][1] += av.y * bv.y;
        acc[1][2] += av.y * bv.z; acc[1][3] += av.y * bv.w;
        acc[2][0] += av.z * bv.x; acc[2][1] += av.z * bv.y;
        acc[2][2] += av.z * bv.z; acc[2][3] += av.z * bv.w;
        acc[3][0] += av.w * bv.x; acc[3][1] += av.w * bv.y;
        acc[3][2] += av.w * bv.z; acc[3][3] += av.w * bv.w;
      }
    }
#pragma unroll
    for (int i = 0; i < 4; ++i) {
      const int row = ty * 4 + i;
#pragma unroll
      for (int j = 0; j < 4; ++j) {
        const int col = tx * 4 + j;
        Sc[row][col] = y2g[cbase + col] - 2.0f * acc[i][j];
      }
    }
    __syncthreads();
    if (tid < 64) {
      for (int c = 0; c < 64; ++c) {
        const float s = Sc[tid][c];
        if (s < top_s[7]) {
          top_s[7] = s; top_i[7] = cbase + c;
#pragma unroll
          for (int j = 7; j > 0; --j) {
            if (top_s[j] < top_s[j - 1]) {
              const float tss = top_s[j]; top_s[j] = top_s[j - 1]; top_s[j - 1] = tss;
              const int tii = top_i[j]; top_i[j] = top_i[j - 1]; top_i[j - 1] = tii;
            }
          }
        }
      }
    }
  }

  if (tid < 64) {
    const int n = r0 + tid;
    const int base = (n * gridDim.x + blockIdx.x) * 8;
#pragma unroll
    for (int j = 0; j < 8; ++j) {
      cand_s[base + j] = top_s[j];
      cand_i[base + j] = top_i[j];
    }
  }
}

__global__ __launch_bounds__(256) void finalize_kernel(
    const float* __restrict__ A, const float* __restrict__ B,
    const float* __restrict__ cand_s, const int* __restrict__ cand_i,
    float* __restrict__ out, int nchunks) {
  const int n = blockIdx.x;
  const int tid = threadIdx.x;
  __shared__ float red[256];
  __shared__ float ls[64];
  __shared__ int li[64];
  __shared__ float wsh2[8];
  __shared__ int wid[8];
  __shared__ float wsum_sh;

  const int ncand = nchunks * 8;
  const float4 a = *(const float4*)&A[(size_t)n * 1024 + tid * 4];
  red[tid] = a.x * a.x + a.y * a.y + a.z * a.z + a.w * a.w;
  if (tid < ncand) {
    ls[tid] = cand_s[n * ncand + tid];
    li[tid] = cand_i[n * ncand + tid];
  }
  __syncthreads();
  for (int s = 128; s > 0; s >>= 1) {
    if (tid < s) red[tid] += red[tid + s];
    __syncthreads();
  }
  if (tid == 0) {
    const float x2 = red[0];
    float wsum = 0.0f;
    for (int j = 0; j < 8; ++j) {
      float bs = SENTINEL;
      int bi = 0x7fffffff;
      int bp = 0;
      for (int c = 0; c < ncand; ++c) {
        const float s_ = ls[c];
        const int i_ = li[c];
        if (s_ < bs || (s_ == bs && i_ < bi)) { bs = s_; bi = i_; bp = c; }
      }
      ls[bp] = SENTINEL; li[bp] = 0x7fffffff;
      float d2 = x2 + bs;
      d2 = fmaxf(d2, 1e-12f);
      const float wkk = 1.0f / (sqrtf(d2) + 0.1f);
      wsh2[j] = wkk; wid[j] = bi;
      wsum += wkk;
    }
    wsum_sh = wsum;
  }
  __syncthreads();
  const float inv = 1.0f / wsum_sh;
  float ox = 0.0f, oy = 0.0f, oz = 0.0f, ow = 0.0f;
#pragma unroll
  for (int j = 0; j < 8; ++j) {
    const float wkk = wsh2[j];
    const float4 v = *(const float4*)&B[(size_t)wid[j] * 1024 + tid * 4];
    ox += wkk * v.x; oy += wkk * v.y; oz += wkk * v.z; ow += wkk * v.w;
  }
  float4 o;
  o.x = ox * inv; o.y = oy * inv; o.z = oz * inv; o.w = ow * inv;
  *(float4*)&out[(size_t)n * 1024 + tid * 4] = o;
}

extern "C" void kernel_launch(void* const* d_in, const int* in_sizes, int n_in,
                              void* d_out, int out_size, void* d_ws, size_t ws_size,
                              hipStream_t stream) {
  const float* A = (const float*)d_in[0];
  const float* Bm = (const float*)d_in[1];
  const int D = 1024;
  const int N = in_sizes[0] / D;  // 4096
  const int M = in_sizes[1] / D;  // 8192

  const size_t needA = (size_t)N * D * 2;
  const size_t needB = (size_t)M * D * 2;
  const size_t needC = (size_t)N * 512 * 4;  // cand_s (== cand_i)
  const size_t need = needA + needB + (size_t)M * 4 + 2 * needC;

  if (ws_size >= need && M == 8192 && N % 128 == 0 && N % 2 == 0) {
    unsigned short* Abf = (unsigned short*)d_ws;
    unsigned short* Bbf = Abf + (size_t)N * D;
    float* y2 = (float*)(Bbf + (size_t)M * D);
    float* cand_s = y2 + M;
    int* cand_i = (int*)(cand_s + (size_t)N * 512);

    convert_all_kernel<<<N + M, 256, 0, stream>>>(A, Bm, Abf, Bbf, y2, N);
    dim3 g(M / 512, N / 128);
    screen4_kernel<<<g, 256, 0, stream>>>(Abf, Bbf, y2, cand_s, cand_i);
    finalize4_kernel<<<N / 2, 256, 0, stream>>>(A, Bm, y2, cand_s, cand_i,
                                                (float*)d_out);
  } else {
    float* y2 = (float*)d_ws;
    float* cand_s = y2 + M;
    int* cand_i = (int*)(cand_s + (size_t)N * 64);
    rownorm_kernel<<<M, 256, 0, stream>>>(Bm, y2);
    dim3 gridB(M / 1024, N / 64);
    knn_chunk_kernel<<<gridB, 256, 0, stream>>>(A, Bm, y2, cand_s, cand_i);
    finalize_kernel<<<N, 256, 0, stream>>>(A, Bm, cand_s, cand_i, (float*)d_out, M / 1024);
  }
}

// Round 7
// 341.690 us; speedup vs baseline: 1.1614x; 1.0109x over previous
//
#include <hip/hip_runtime.h>

// KNN (K=8) + inverse-distance-weighted average, MFMA screening version.
// data1: [N=4096, D=1024] fp32, data2: [M=8192, D=1024] fp32, out: [N, D] fp32.
//
// Fast path:
//  1) convert_all: A -> bf16; B -> bf16 fused with y2[m]=||B[m]||^2
//  2) screen5: bf16 MFMA GEMM, 128x256 tile x2 chunks/block, XCD-aware block
//     swizzle (per-XCD B working set 2 MB -> L2-resident), LDS double-buffered
//     glds prefetch (stage k+1 during compute k), SWAPPED operands ->
//     row-per-lane C/D, barrier-free top-8 epilogue. 512 cands/row.
//  3) finalize4: 2 waves per row; 512 cands -> approx top-12 -> EXACT fp32
//     rescore -> top-8 by (d2, idx) -> w = 1/(sqrt(max(d2,1e-12))+0.1) ->
//     weighted gather.
// Fallback (small ws): round-1 pure-fp32 path (verified correct).

typedef short bf16x8 __attribute__((ext_vector_type(8)));
typedef float f32x4 __attribute__((ext_vector_type(4)));

#define SENTINEL 1e30f
#define BKK 32

static __device__ __forceinline__ unsigned short f2bf(float f) {
  unsigned u = __float_as_uint(f);
  return (unsigned short)((u + 0x7fffu + ((u >> 16) & 1u)) >> 16);
}

// ---------------- fast path kernels ----------------
// grid: N + M blocks. bid < N: convert A row. else: convert B row + norm.
__global__ __launch_bounds__(256) void convert_all_kernel(
    const float* __restrict__ A, const float* __restrict__ B,
    unsigned short* __restrict__ Abf, unsigned short* __restrict__ Bbf,
    float* __restrict__ y2, int N) {
  const int bid = blockIdx.x;
  const int tid = threadIdx.x;
  if (bid < N) {
    const float4 v = ((const float4*)&A[(size_t)bid * 1024])[tid];
    ushort4 o;
    o.x = f2bf(v.x); o.y = f2bf(v.y); o.z = f2bf(v.z); o.w = f2bf(v.w);
    ((ushort4*)&Abf[(size_t)bid * 1024])[tid] = o;
  } else {
    const int m = bid - N;
    __shared__ float red[256];
    const float4 v = ((const float4*)&B[(size_t)m * 1024])[tid];
    ushort4 o;
    o.x = f2bf(v.x); o.y = f2bf(v.y); o.z = f2bf(v.z); o.w = f2bf(v.w);
    ((ushort4*)&Bbf[(size_t)m * 1024])[tid] = o;
    red[tid] = v.x * v.x + v.y * v.y + v.z * v.z + v.w * v.w;
    __syncthreads();
    for (int s = 128; s > 0; s >>= 1) {
      if (tid < s) red[tid] += red[tid + s];
      __syncthreads();
    }
    if (tid == 0) y2[m] = red[0];
  }
}

// ascending compare-exchange on (s, i) register pairs
#define CAS(sa, ia, sb, ib)                         \
  do {                                              \
    if ((sa) > (sb)) {                              \
      const float _t = (sa); (sa) = (sb); (sb) = _t;\
      const int _u = (ia); (ia) = (ib); (ib) = _u;  \
    }                                               \
  } while (0)

// stage k-slice sk (k0 = sk*32) of current chunk into LDS buffer b
#define STAGE(sk, b)                                                          \
  do {                                                                        \
    const unsigned short* gA_ =                                               \
        Abf + (size_t)(r0 + w * 32 + srow) * 1024 + (sk) * 32 + sofs;         \
    const unsigned short* gB_ =                                               \
        Bbf + (size_t)(c0 + w * 64 + srow) * 1024 + (sk) * 32 + sofs;         \
    __builtin_amdgcn_global_load_lds(                                         \
        (const __attribute__((address_space(1))) void*)gA_,                   \
        (__attribute__((address_space(3))) void*)&As[b][(w * 32) * 32],       \
        16, 0, 0);                                                            \
    __builtin_amdgcn_global_load_lds(                                         \
        (const __attribute__((address_space(1))) void*)(gA_ + (size_t)16 * 1024), \
        (__attribute__((address_space(3))) void*)&As[b][(w * 32 + 16) * 32],  \
        16, 0, 0);                                                            \
    _Pragma("unroll")                                                         \
    for (int l_ = 0; l_ < 4; ++l_)                                            \
      __builtin_amdgcn_global_load_lds(                                       \
          (const __attribute__((address_space(1))) void*)(gB_ + (size_t)(16 * l_) * 1024), \
          (__attribute__((address_space(3))) void*)&Bs[b][(w * 64 + 16 * l_) * 32], \
          16, 0, 0);                                                          \
  } while (0)

#define COMPUTE(b)                                                            \
  do {                                                                        \
    bf16x8 af[4], bfr[8];                                                     \
    _Pragma("unroll")                                                         \
    for (int fi = 0; fi < 4; ++fi)                                            \
      af[fi] = *(const bf16x8*)&As[b][(frowA + fi * 16) * 32 + fofs];         \
    _Pragma("unroll")                                                         \
    for (int fj = 0; fj < 8; ++fj)                                            \
      bfr[fj] = *(const bf16x8*)&Bs[b][(frowB + fj * 16) * 32 + fofs];        \
    _Pragma("unroll")                                                         \
    for (int fi = 0; fi < 4; ++fi)                                            \
      _Pragma("unroll")                                                       \
      for (int fj = 0; fj < 8; ++fj)                                          \
        acc[fi][fj] = __builtin_amdgcn_mfma_f32_16x16x32_bf16(                \
            bfr[fj], af[fi], acc[fi][fj], 0, 0, 0);                           \
  } while (0)

// grid: (16, 32) = 512 blocks (one occupancy round at 2 blocks/CU).
// XCD swizzle: v%8 = XCD (round-robin dispatch assumption; perf-only);
// XCD i owns B-chunks {2i, 2i+1} -> 2 MB B + ~2 MB A per XCD L2.
// Per chunk: 128x256 tile, acc[4][8], SWAPPED MFMA operands, LDS dbuf
// prefetch; barrier-free top-8 epilogue. LDS XOR swizzle on k-chunks.
__global__ __launch_bounds__(256, 2) void screen5_kernel(
    const unsigned short* __restrict__ Abf, const unsigned short* __restrict__ Bbf,
    const float* __restrict__ y2g,
    float* __restrict__ cand_s, int* __restrict__ cand_i) {
  __shared__ unsigned short As[2][128 * 32];  // 16 KB
  __shared__ unsigned short Bs[2][256 * 32];  // 32 KB
  __shared__ float y2sh[256];

  const int tid = threadIdx.x;
  const int w = tid >> 6;
  const int lane = tid & 63;
  const int wr = w >> 1, wc = w & 1;

  const int v = blockIdx.x + gridDim.x * blockIdx.y;
  const int bx = (v & 7) * 2 + ((v >> 3) & 1);
  const int by = v >> 4;
  const int r0 = by * 128;

  // staging: lane -> LDS slot (16 rows per glds), swizzle on global source
  const int srow = lane >> 2;                          // 0..15
  const int sofs = ((lane & 3) ^ ((lane >> 3) & 3)) * 8;

  // fragment reads: LDS col = kc ^ ((row>>1)&3), kc = lane>>4
  const int frowA = wr * 64 + (lane & 15);
  const int frowB = wc * 128 + (lane & 15);
  const int fofs = ((lane >> 4) ^ ((lane >> 1) & 3)) * 8;
  const int cgrp = (lane >> 4) * 4;

  for (int chunk = 0; chunk < 2; ++chunk) {
    const int c0 = bx * 512 + chunk * 256;
    __syncthreads();  // prev chunk's epilogue/LDS readers done
    y2sh[tid] = y2g[c0 + tid];

    f32x4 acc[4][8];
#pragma unroll
    for (int fi = 0; fi < 4; ++fi)
#pragma unroll
      for (int fj = 0; fj < 8; ++fj) {
        f32x4 z = {0.f, 0.f, 0.f, 0.f};
        acc[fi][fj] = z;
      }

    STAGE(0, 0);
    for (int kk = 0; kk < 32; kk += 2) {
      __syncthreads();       // buf0 (slice kk) staged & visible
      STAGE(kk + 1, 1);      // prefetch next slice during compute
      COMPUTE(0);
      __syncthreads();       // buf1 (slice kk+1) staged & visible
      if (kk + 2 < 32) STAGE(kk + 2, 0);
      COMPUTE(1);
    }

    // barrier-free epilogue. Lane's cands: row = r0+wr*64+fi*16+(lane&15),
    // col = c0 + wc*128 + fj*16 + cgrp + reg.
    float4 y2v[8];
#pragma unroll
    for (int fj = 0; fj < 8; ++fj)
      y2v[fj] = *(const float4*)&y2sh[wc * 128 + fj * 16 + cgrp];

#pragma unroll
    for (int fi = 0; fi < 4; ++fi) {
      float ls[8];
      int li[8];
#pragma unroll
      for (int j = 0; j < 8; ++j) { ls[j] = SENTINEL; li[j] = 0x7fffffff; }
      const int cb = c0 + wc * 128 + cgrp;
#pragma unroll
      for (int fj = 0; fj < 8; ++fj) {
#pragma unroll
        for (int reg = 0; reg < 4; ++reg) {
          const float s = y2v[fj][reg] - 2.0f * acc[fi][fj][reg];
          if (s < ls[7]) {
            ls[7] = s; li[7] = cb + fj * 16 + reg;
#pragma unroll
            for (int j = 7; j > 0; --j) {
              if (ls[j] < ls[j - 1]) {
                const float t = ls[j]; ls[j] = ls[j - 1]; ls[j - 1] = t;
                const int u = li[j]; li[j] = li[j - 1]; li[j - 1] = u;
              }
            }
          }
        }
      }
      // merge sorted 8-lists across the 4 lanes sharing this row
#pragma unroll
      for (int off = 16; off <= 32; off <<= 1) {
        float rs[8];
        int ri[8];
#pragma unroll
        for (int j = 0; j < 8; ++j) {
          rs[j] = __shfl_xor(ls[j], off, 64);
          ri[j] = __shfl_xor(li[j], off, 64);
        }
        float ms[8];
        int mi_[8];
#pragma unroll
        for (int i = 0; i < 8; ++i) {
          const bool t = ls[i] < rs[7 - i];
          ms[i] = t ? ls[i] : rs[7 - i];
          mi_[i] = t ? li[i] : ri[7 - i];
        }
        CAS(ms[0], mi_[0], ms[4], mi_[4]);
        CAS(ms[1], mi_[1], ms[5], mi_[5]);
        CAS(ms[2], mi_[2], ms[6], mi_[6]);
        CAS(ms[3], mi_[3], ms[7], mi_[7]);
        CAS(ms[0], mi_[0], ms[2], mi_[2]);
        CAS(ms[1], mi_[1], ms[3], mi_[3]);
        CAS(ms[4], mi_[4], ms[6], mi_[6]);
        CAS(ms[5], mi_[5], ms[7], mi_[7]);
        CAS(ms[0], mi_[0], ms[1], mi_[1]);
        CAS(ms[2], mi_[2], ms[3], mi_[3]);
        CAS(ms[4], mi_[4], ms[5], mi_[5]);
        CAS(ms[6], mi_[6], ms[7], mi_[7]);
#pragma unroll
        for (int j = 0; j < 8; ++j) { ls[j] = ms[j]; li[j] = mi_[j]; }
      }
      if ((lane >> 4) == 0) {  // lanes 0..15 hold the merged per-row top-8
        const int row = r0 + wr * 64 + fi * 16 + lane;
        const size_t base =
            ((size_t)row * 64 + wc * 32 + bx * 2 + chunk) * 8;
#pragma unroll
        for (int j = 0; j < 8; ++j) {
          cand_s[base + j] = ls[j];
          cand_i[base + j] = li[j];
        }
      }
    }
  }
}

// 2 waves per row: grid N/2 blocks x 256 threads (4 waves = 2 rows x 2
// wave-halves). 512 cand -> approx top-12 -> exact fp32 rescore
// (position-interleaved) -> top-8 -> weighted gather.
// Lane covers 8 contiguous elements: float4 idx = wh*128 + lane*2 + {0,1}.
__global__ __launch_bounds__(256) void finalize4_kernel(
    const float* __restrict__ A, const float* __restrict__ B,
    const float* __restrict__ y2g,
    const float* __restrict__ cand_s, const int* __restrict__ cand_i,
    float* __restrict__ out) {
  const int tid = threadIdx.x;
  const int w = tid >> 6;
  const int lane = tid & 63;
  const int rloc = w >> 1;  // row within block
  const int wh = w & 1;     // wave-half along D
  const int n = blockIdx.x * 2 + rloc;
  __shared__ int mi[2][512];
  __shared__ float comb[2][2][16];

  // both waves of a row build identical keys; wh==0 publishes indices
  unsigned long long key[8];
#pragma unroll
  for (int i = 0; i < 8; ++i) {
    const int slot = lane + 64 * i;
    const float s = cand_s[(size_t)n * 512 + slot];
    if (wh == 0) mi[rloc][slot] = cand_i[(size_t)n * 512 + slot];
    unsigned u = __float_as_uint(s);
    u = (u & 0x80000000u) ? ~u : (u | 0x80000000u);
    key[i] = ((unsigned long long)u << 32) | (unsigned)slot;
  }
  __syncthreads();

  int ci[12];
  for (int r = 0; r < 12; ++r) {
    unsigned long long kb = key[0];
#pragma unroll
    for (int i = 1; i < 8; ++i) kb = key[i] < kb ? key[i] : kb;
#pragma unroll
    for (int off = 32; off >= 1; off >>= 1) {
      const unsigned long long o = __shfl_xor(kb, off, 64);
      kb = o < kb ? o : kb;
    }
    const int slot = (int)(kb & 0xffffffffu);
    ci[r] = mi[rloc][slot];
#pragma unroll
    for (int i = 0; i < 8; ++i)
      if (slot == lane + 64 * i) key[i] = ~0ull;
  }

  // exact fp32 partial dots; position-interleaved for deep MLP
  const float4* Arow = (const float4*)&A[(size_t)n * 1024];
  const int fbase = wh * 128 + lane * 2;
  float4 a4[2];
  a4[0] = Arow[fbase];
  a4[1] = Arow[fbase + 1];
  float part[13];
#pragma unroll
  for (int r = 0; r < 13; ++r) part[r] = 0.0f;
  part[12] = a4[0].x * a4[0].x + a4[0].y * a4[0].y + a4[0].z * a4[0].z +
             a4[0].w * a4[0].w + a4[1].x * a4[1].x + a4[1].y * a4[1].y +
             a4[1].z * a4[1].z + a4[1].w * a4[1].w;
#pragma unroll
  for (int p = 0; p < 2; ++p) {
    float4 b[12];
#pragma unroll
    for (int j = 0; j < 12; ++j)
      b[j] = ((const float4*)&B[(size_t)ci[j] * 1024])[fbase + p];
#pragma unroll
    for (int j = 0; j < 12; ++j)
      part[j] += a4[p].x * b[j].x + a4[p].y * b[j].y + a4[p].z * b[j].z +
                 a4[p].w * b[j].w;
  }
#pragma unroll
  for (int r = 0; r < 13; ++r) {
#pragma unroll
    for (int off = 32; off >= 1; off >>= 1) part[r] += __shfl_xor(part[r], off, 64);
  }
  if (lane == 0) {
#pragma unroll
    for (int r = 0; r < 13; ++r) comb[rloc][wh][r] = part[r];
  }
  __syncthreads();
  float tot[13];
#pragma unroll
  for (int r = 0; r < 13; ++r) tot[r] = comb[rloc][0][r] + comb[rloc][1][r];

  // uniform redundant selection: top-8 by (d2, idx)
  const float x2 = tot[12];
  float d2v[12];
  bool used[12];
#pragma unroll
  for (int j = 0; j < 12; ++j) {
    d2v[j] = x2 + y2g[ci[j]] - 2.0f * tot[j];
    used[j] = false;
  }
  float wk[8];
  int wi[8];
  float wsum = 0.0f;
  for (int k = 0; k < 8; ++k) {
    float bd = SENTINEL;
    int bi = 0x7fffffff, bslot = 0;
#pragma unroll
    for (int j = 0; j < 12; ++j) {
      if (used[j]) continue;
      const float d2 = d2v[j];
      if (d2 < bd || (d2 == bd && ci[j] < bi)) { bd = d2; bi = ci[j]; bslot = j; }
    }
    used[bslot] = true;
    const float d2c = fmaxf(bd, 1e-12f);
    const float wv = 1.0f / (sqrtf(d2c) + 0.1f);
    wk[k] = wv; wi[k] = bi; wsum += wv;
  }
  const float inv = 1.0f / wsum;

  float4 o0 = {0, 0, 0, 0}, o1 = {0, 0, 0, 0};
#pragma unroll
  for (int k = 0; k < 8; ++k) {
    const float wv = wk[k];
    const float4* Brow = (const float4*)&B[(size_t)wi[k] * 1024];
    const float4 b0 = Brow[fbase];
    const float4 b1 = Brow[fbase + 1];
    o0.x += wv * b0.x; o0.y += wv * b0.y; o0.z += wv * b0.z; o0.w += wv * b0.w;
    o1.x += wv * b1.x; o1.y += wv * b1.y; o1.z += wv * b1.z; o1.w += wv * b1.w;
  }
  o0.x *= inv; o0.y *= inv; o0.z *= inv; o0.w *= inv;
  o1.x *= inv; o1.y *= inv; o1.z *= inv; o1.w *= inv;
  float4* Orow = (float4*)&out[(size_t)n * 1024];
  Orow[fbase] = o0;
  Orow[fbase + 1] = o1;
}

// ---------------- fallback path (round-1, verified) ----------------
__global__ __launch_bounds__(256) void rownorm_kernel(
    const float* __restrict__ B, float* __restrict__ y2) {
  const int m = blockIdx.x;
  const int tid = threadIdx.x;
  __shared__ float red[256];
  const float4 v = *(const float4*)&B[(size_t)m * 1024 + tid * 4];
  red[tid] = v.x * v.x + v.y * v.y + v.z * v.z + v.w * v.w;
  __syncthreads();
  for (int s = 128; s > 0; s >>= 1) {
    if (tid < s) red[tid] += red[tid + s];
    __syncthreads();
  }
  if (tid == 0) y2[m] = red[0];
}

__global__ __launch_bounds__(256) void knn_chunk_kernel(
    const float* __restrict__ A, const float* __restrict__ B,
    const float* __restrict__ y2g,
    float* __restrict__ cand_s, int* __restrict__ cand_i) {
  __shared__ float As[BKK][68];
  __shared__ float Bs[BKK][68];
  __shared__ float Sc[64][65];

  const int tid = threadIdx.x;
  const int tx = tid & 15;
  const int ty = tid >> 4;
  const int r0 = blockIdx.y * 64;
  const int c0 = blockIdx.x * 1024;
  const int lrow = tid >> 3;
  const int lk = (tid & 7) * 4;

  float top_s[8];
  int top_i[8];
#pragma unroll
  for (int j = 0; j < 8; ++j) { top_s[j] = SENTINEL; top_i[j] = 0x7fffffff; }

  for (int tile = 0; tile < 16; ++tile) {
    const int cbase = c0 + tile * 64;
    float acc[4][4];
#pragma unroll
    for (int i = 0; i < 4; ++i)
#pragma unroll
      for (int j = 0; j < 4; ++j) acc[i][j] = 0.0f;

    for (int k0 = 0; k0 < 1024; k0 += BKK) {
      const float4 a0 = *(const float4*)&A[(size_t)(r0 + lrow) * 1024 + k0 + lk];
      const float4 a1 = *(const float4*)&A[(size_t)(r0 + lrow + 32) * 1024 + k0 + lk];
      const float4 b0 = *(const float4*)&B[(size_t)(cbase + lrow) * 1024 + k0 + lk];
      const float4 b1 = *(const float4*)&B[(size_t)(cbase + lrow + 32) * 1024 + k0 + lk];
      __syncthreads();
      As[lk + 0][lrow] = a0.x; As[lk + 1][lrow] = a0.y;
      As[lk + 2][lrow] = a0.z; As[lk + 3][lrow] = a0.w;
      As[lk + 0][lrow + 32] = a1.x; As[lk + 1][lrow + 32] = a1.y;
      As[lk + 2][lrow + 32] = a1.z; As[lk + 3][lrow + 32] = a1.w;
      Bs[lk + 0][lrow] = b0.x; Bs[lk + 1][lrow] = b0.y;
      Bs[lk + 2][lrow] = b0.z; Bs[lk + 3][lrow] = b0.w;
      Bs[lk + 0][lrow + 32] = b1.x; Bs[lk + 1][lrow + 32] = b1.y;
      Bs[lk + 2][lrow + 32] = b1.z; Bs[lk + 3][lrow + 32] = b1.w;
      __syncthreads();
#pragma unroll
      for (int kk = 0; kk < BKK; ++kk) {
        const float4 av = *(const float4*)&As[kk][ty * 4];
        const float4 bv = *(const float4*)&Bs[kk][tx * 4];
        acc[0][0] += av.x * bv.x; acc[0][1] += av.x * bv.y;
        acc[0][2] += av.x * bv.z; acc[0][3] += av.x * bv.w;
        acc[1][0] += av.y * bv.x; acc[1][1] += av.y * bv.y;
        acc[1][2] += av.y * bv.z; acc[1][3] += av.y * bv.w;
        acc[2][0] += av.z * bv.x; acc[2][1] += av.z * bv.y;
        acc[2][2] += av.z * bv.z; acc[2][3] += av.z * bv.w;
        acc[3][0] += av.w * bv.x; acc[3][1] += av.w * bv.y;
        acc[3][2] += av.w * bv.z; acc[3][3] += av.w * bv.w;
      }
    }
#pragma unroll
    for (int i = 0; i < 4; ++i) {
      const int row = ty * 4 + i;
#pragma unroll
      for (int j = 0; j < 4; ++j) {
        const int col = tx * 4 + j;
        Sc[row][col] = y2g[cbase + col] - 2.0f * acc[i][j];
      }
    }
    __syncthreads();
    if (tid < 64) {
      for (int c = 0; c < 64; ++c) {
        const float s = Sc[tid][c];
        if (s < top_s[7]) {
          top_s[7] = s; top_i[7] = cbase + c;
#pragma unroll
          for (int j = 7; j > 0; --j) {
            if (top_s[j] < top_s[j - 1]) {
              const float tss = top_s[j]; top_s[j] = top_s[j - 1]; top_s[j - 1] = tss;
              const int tii = top_i[j]; top_i[j] = top_i[j - 1]; top_i[j - 1] = tii;
            }
          }
        }
      }
    }
  }

  if (tid < 64) {
    const int n = r0 + tid;
    const int base = (n * gridDim.x + blockIdx.x) * 8;
#pragma unroll
    for (int j = 0; j < 8; ++j) {
      cand_s[base + j] = top_s[j];
      cand_i[base + j] = top_i[j];
    }
  }
}

__global__ __launch_bounds__(256) void finalize_kernel(
    const float* __restrict__ A, const float* __restrict__ B,
    const float* __restrict__ cand_s, const int* __restrict__ cand_i,
    float* __restrict__ out, int nchunks) {
  const int n = blockIdx.x;
  const int tid = threadIdx.x;
  __shared__ float red[256];
  __shared__ float ls[64];
  __shared__ int li[64];
  __shared__ float wsh2[8];
  __shared__ int wid[8];
  __shared__ float wsum_sh;

  const int ncand = nchunks * 8;
  const float4 a = *(const float4*)&A[(size_t)n * 1024 + tid * 4];
  red[tid] = a.x * a.x + a.y * a.y + a.z * a.z + a.w * a.w;
  if (tid < ncand) {
    ls[tid] = cand_s[n * ncand + tid];
    li[tid] = cand_i[n * ncand + tid];
  }
  __syncthreads();
  for (int s = 128; s > 0; s >>= 1) {
    if (tid < s) red[tid] += red[tid + s];
    __syncthreads();
  }
  if (tid == 0) {
    const float x2 = red[0];
    float wsum = 0.0f;
    for (int j = 0; j < 8; ++j) {
      float bs = SENTINEL;
      int bi = 0x7fffffff;
      int bp = 0;
      for (int c = 0; c < ncand; ++c) {
        const float s_ = ls[c];
        const int i_ = li[c];
        if (s_ < bs || (s_ == bs && i_ < bi)) { bs = s_; bi = i_; bp = c; }
      }
      ls[bp] = SENTINEL; li[bp] = 0x7fffffff;
      float d2 = x2 + bs;
      d2 = fmaxf(d2, 1e-12f);
      const float wkk = 1.0f / (sqrtf(d2) + 0.1f);
      wsh2[j] = wkk; wid[j] = bi;
      wsum += wkk;
    }
    wsum_sh = wsum;
  }
  __syncthreads();
  const float inv = 1.0f / wsum_sh;
  float ox = 0.0f, oy = 0.0f, oz = 0.0f, ow = 0.0f;
#pragma unroll
  for (int j = 0; j < 8; ++j) {
    const float wkk = wsh2[j];
    const float4 v = *(const float4*)&B[(size_t)wid[j] * 1024 + tid * 4];
    ox += wkk * v.x; oy += wkk * v.y; oz += wkk * v.z; ow += wkk * v.w;
  }
  float4 o;
  o.x = ox * inv; o.y = oy * inv; o.z = oz * inv; o.w = ow * inv;
  *(float4*)&out[(size_t)n * 1024 + tid * 4] = o;
}

extern "C" void kernel_launch(void* const* d_in, const int* in_sizes, int n_in,
                              void* d_out, int out_size, void* d_ws, size_t ws_size,
                              hipStream_t stream) {
  const float* A = (const float*)d_in[0];
  const float* Bm = (const float*)d_in[1];
  const int D = 1024;
  const int N = in_sizes[0] / D;  // 4096
  const int M = in_sizes[1] / D;  // 8192

  const size_t needA = (size_t)N * D * 2;
  const size_t needB = (size_t)M * D * 2;
  const size_t needC = (size_t)N * 512 * 4;  // cand_s (== cand_i)
  const size_t need = needA + needB + (size_t)M * 4 + 2 * needC;

  if (ws_size >= need && M == 8192 && N % 128 == 0 && N % 2 == 0) {
    unsigned short* Abf = (unsigned short*)d_ws;
    unsigned short* Bbf = Abf + (size_t)N * D;
    float* y2 = (float*)(Bbf + (size_t)M * D);
    float* cand_s = y2 + M;
    int* cand_i = (int*)(cand_s + (size_t)N * 512);

    convert_all_kernel<<<N + M, 256, 0, stream>>>(A, Bm, Abf, Bbf, y2, N);
    dim3 g(M / 512, N / 128);
    screen5_kernel<<<g, 256, 0, stream>>>(Abf, Bbf, y2, cand_s, cand_i);
    finalize4_kernel<<<N / 2, 256, 0, stream>>>(A, Bm, y2, cand_s, cand_i,
                                                (float*)d_out);
  } else {
    float* y2 = (float*)d_ws;
    float* cand_s = y2 + M;
    int* cand_i = (int*)(cand_s + (size_t)N * 64);
    rownorm_kernel<<<M, 256, 0, stream>>>(Bm, y2);
    dim3 gridB(M / 1024, N / 64);
    knn_chunk_kernel<<<gridB, 256, 0, stream>>>(A, Bm, y2, cand_s, cand_i);
    finalize_kernel<<<N, 256, 0, stream>>>(A, Bm, cand_s, cand_i, (float*)d_out, M / 1024);
  }
}